// Round 8
// baseline (54940.692 us; speedup 1.0000x reference)
//
#include <hip/hip_runtime.h>
#include <math.h>

#define B_ 128
#define T_ 128
#define IN_ 75
#define H_ 512
#define C_ 60
#define Q_ 25

// ---------------- workspace layout (bytes) ----------------
constexpr size_t OFF_WXTP = 0;         // uint4 [ug][m] bf16 pairs {W_x_t,W_h_t,W_x_s,W_h_s}; m=(j*4+q), lo=k(8j+q), hi=k+4
constexpr size_t OFF_WIHP = 2097152;   // uint4 [ug][k]  bf16 {it|ft, gt|ot, is|fs, gs|os}
constexpr size_t OFF_FTP  = 2711552;   // uint  [ug][k]  bf16 {fct|fc1}
constexpr size_t OFF_W1P  = 2865152;   // uint2 [ug][k]  bf16 {i1|f1, g1|o1}
constexpr size_t OFF_U2   = 3172352;   // float [25][512]  (U_s @ fc2_w.T)
constexpr size_t OFF_B2   = 3223552;   // float [32]
constexpr size_t OFF_SPA  = 3223680;   // float4 [k=unit][bg] {h_t,h_s,tmp1,tmp2} (accessed as 2x float2 sc1)
constexpr size_t OFF_H1   = 4272256;   // float [k][bg]
constexpr size_t OFF_ST   = 4534400;   // float [b][j]
constexpr size_t OFF_AL   = 4796544;   // float [b][25]
constexpr size_t OFF_FLG  = 4809344;   // unsigned flags, 256 x 64B; GO word on its own line
constexpr size_t WS_BYTES = 4826752;

#define GO_IDX 4112                    // own 64B line, past flag 255

struct Full {
  const float* inputs;
  const float* Wih_t; const float* Whh_t; const float* bih_t; const float* bhh_t;
  const float* Wih_s; const float* Whh_s; const float* bih_s; const float* bhh_s;
  const float* Wih_1; const float* Whh_1; const float* bih_1; const float* bhh_1;
  const float* fc_w;  const float* fc_b;
  const float* fct_w; const float* fct_b;
  const float* fc1_w; const float* fc1_b;
  const float* fc2_w; const float* fc2_b;
  const float* W_x_t; const float* W_h_t; const float* b_t;
  const float* W_x_s; const float* W_h_s; const float* U_s; const float* b_s; const float* b_us;
  char* ws; float* out;
};

__device__ __forceinline__ float sigm(float v) { return 1.f / (1.f + expf(-v)); }
__device__ __forceinline__ float blo(unsigned d) { return __uint_as_float(d << 16); }
__device__ __forceinline__ float bhi(unsigned d) { return __uint_as_float(d & 0xffff0000u); }
__device__ __forceinline__ unsigned short tob(float f) {
  unsigned u = __float_as_uint(f);
  return (unsigned short)((u + 0x7fffu + ((u >> 16) & 1u)) >> 16);
}
__device__ __forceinline__ unsigned pack2(float lo, float hi) {
  return (unsigned)tob(lo) | ((unsigned)tob(hi) << 16);
}

// device-coherent (L3-point, sc1) relaxed accessors
__device__ __forceinline__ float2 lda2(const void* p) {
  unsigned long long v = __hip_atomic_load((const unsigned long long*)p,
                                           __ATOMIC_RELAXED, __HIP_MEMORY_SCOPE_AGENT);
  union { unsigned long long u; float2 f; } c; c.u = v; return c.f;
}
__device__ __forceinline__ void sta2(void* p, float2 x) {
  union { float2 f; unsigned long long u; } c; c.f = x;
  __hip_atomic_store((unsigned long long*)p, c.u, __ATOMIC_RELAXED, __HIP_MEMORY_SCOPE_AGENT);
}
__device__ __forceinline__ float lda1(const void* p) {
  unsigned v = __hip_atomic_load((const unsigned*)p, __ATOMIC_RELAXED, __HIP_MEMORY_SCOPE_AGENT);
  return __uint_as_float(v);
}
__device__ __forceinline__ void sta1(void* p, float x) {
  __hip_atomic_store((unsigned*)p, __float_as_uint(x), __ATOMIC_RELAXED, __HIP_MEMORY_SCOPE_AGENT);
}

// ---------------- prep: pack weights ----------------
__global__ void prep_pack(Full f) {
  uint4* WXTP = (uint4*)(f.ws + OFF_WXTP);
  uint4* WIHP = (uint4*)(f.ws + OFF_WIHP);
  unsigned* FTP = (unsigned*)(f.ws + OFF_FTP);
  uint2* W1P = (uint2*)(f.ws + OFF_W1P);
  float* U2 = (float*)(f.ws + OFF_U2);
  float* B2 = (float*)(f.ws + OFF_B2);
  unsigned* FLG = (unsigned*)(f.ws + OFF_FLG);
  for (int i = blockIdx.x * blockDim.x + threadIdx.x; i < 4352; i += gridDim.x * blockDim.x)
    FLG[i] = 0u;

  const size_t N1 = (size_t)512 * 256;   // WXTP (ug,m)
  const size_t N2 = (size_t)512 * 75;    // WIHP
  const size_t N3 = (size_t)512 * 75;    // FTP
  const size_t N4 = (size_t)512 * 75;    // W1P
  const size_t N5 = (size_t)25 * 512;    // U2
  const size_t N6 = 25;                  // B2
  const size_t TOT = N1 + N2 + N3 + N4 + N5 + N6;
  for (size_t i = (size_t)blockIdx.x * blockDim.x + threadIdx.x; i < TOT;
       i += (size_t)gridDim.x * blockDim.x) {
    if (i < N1) {
      size_t ug = i >> 8, m = i & 255;
      size_t j = m >> 2, q = m & 3;
      size_t ka = 8 * j + q, kb = ka + 4;
      uint4 v;
      v.x = pack2(f.W_x_t[ka * 512 + ug], f.W_x_t[kb * 512 + ug]);
      v.y = pack2(f.W_h_t[ka * 512 + ug], f.W_h_t[kb * 512 + ug]);
      v.z = pack2(f.W_x_s[ka * 512 + ug], f.W_x_s[kb * 512 + ug]);
      v.w = pack2(f.W_h_s[ka * 512 + ug], f.W_h_s[kb * 512 + ug]);
      WXTP[ug * 256 + m] = v;
    } else if (i < N1 + N2) {
      size_t j = i - N1; size_t ug = j / 75, k = j % 75;
      uint4 v;
      v.x = pack2(f.Wih_t[ug * 75 + k],          f.Wih_t[(512 + ug) * 75 + k]);
      v.y = pack2(f.Wih_t[(1024 + ug) * 75 + k], f.Wih_t[(1536 + ug) * 75 + k]);
      v.z = pack2(f.Wih_s[ug * 75 + k],          f.Wih_s[(512 + ug) * 75 + k]);
      v.w = pack2(f.Wih_s[(1024 + ug) * 75 + k], f.Wih_s[(1536 + ug) * 75 + k]);
      WIHP[ug * 75 + k] = v;
    } else if (i < N1 + N2 + N3) {
      size_t j = i - N1 - N2; size_t ug = j / 75, k = j % 75;
      FTP[ug * 75 + k] = pack2(f.fct_w[ug * 75 + k], f.fc1_w[ug * 75 + k]);
    } else if (i < N1 + N2 + N3 + N4) {
      size_t j = i - N1 - N2 - N3; size_t ug = j / 75, k = j % 75;
      uint2 v;
      v.x = pack2(f.Wih_1[ug * 75 + k],          f.Wih_1[(512 + ug) * 75 + k]);
      v.y = pack2(f.Wih_1[(1024 + ug) * 75 + k], f.Wih_1[(1536 + ug) * 75 + k]);
      W1P[ug * 75 + k] = v;
    } else if (i < N1 + N2 + N3 + N4 + N5) {
      size_t j = i - N1 - N2 - N3 - N4; size_t qi = j >> 9, col = j & 511;
      float acc = 0.f;
      for (int n = 0; n < 512; ++n) acc = fmaf(f.U_s[col * 512 + n], f.fc2_w[qi * 512 + n], acc);
      U2[qi * 512 + col] = acc;
    } else {
      size_t qi = i - N1 - N2 - N3 - N4 - N5;
      float acc = f.fc2_b[qi];
      for (int n = 0; n < 512; ++n) acc = fmaf(f.b_us[n], f.fc2_w[qi * 512 + n], acc);
      B2[qi] = acc;
    }
  }
}

// ---------------- prep: initial state ----------------
__global__ __launch_bounds__(512) void prep_state(Full f) {
  const int b = blockIdx.x, j = threadIdx.x;
  __shared__ float x0[77];
  if (j < IN_) x0[j] = f.inputs[(size_t)b * T_ * IN_ + j];
  __syncthreads();
  float t1 = f.fct_b[j], t2 = f.fc1_b[j];
  for (int k = 0; k < IN_; ++k) {
    t1 = fmaf(x0[k], f.fct_w[j * IN_ + k], t1);
    t2 = fmaf(x0[k], f.fc1_w[j * IN_ + k], t2);
  }
  float4* SPA4 = (float4*)(f.ws + OFF_SPA);
  SPA4[(size_t)j * 128 + b] = make_float4(0.f, 0.f, t1, t2);
  ((float*)(f.ws + OFF_H1))[(size_t)j * 128 + b] = 0.f;
}

// register-staged prefetch chunk: 8 thread-k's of state
struct Ch { float4 s[8]; float hp[8]; };

__device__ __forceinline__ void ldch(Ch& c, const float2* sp2, const float* h1f,
                                     int i0, int q, int bg) {
#pragma unroll
  for (int ii = 0; ii < 8; ++ii) {
    const int k = 4 * (i0 + ii) + q;
    const size_t e = ((size_t)k * 128 + bg) * 2;
    const float2 lo = lda2(&sp2[e]);
    const float2 hi = lda2(&sp2[e + 1]);
    c.s[ii] = make_float4(lo.x, lo.y, hi.x, hi.y);
    c.hp[ii] = lda1(&h1f[(size_t)k * 128 + bg]);
  }
}

#define PAIR(c, i0c, p) { \
    const int ka = 4 * ((i0c) + 2 * (p)) + q; \
    const int kb = ka + 4; \
    const int mm = (((i0c) >> 1) + (p)) * 4 + q; \
    const float4 s0 = (c).s[2 * (p)]; \
    const float4 s1 = (c).s[2 * (p) + 1]; \
    const float hpa = (c).hp[2 * (p)], hpb = (c).hp[2 * (p) + 1]; \
    const float4 wt0 = *(const float4*)WhhL[0][ka][u]; \
    const float4 wt1 = *(const float4*)WhhL[0][kb][u]; \
    const float4 wv0 = *(const float4*)WhhL[1][ka][u]; \
    const float4 wv1 = *(const float4*)WhhL[1][kb][u]; \
    const float4 w10 = *(const float4*)WhhL[2][ka][u]; \
    const float4 w11 = *(const float4*)WhhL[2][kb][u]; \
    const uint4 wx = WXL[mm][u]; \
    at0 = fmaf(s0.x, wt0.x, at0); at1 = fmaf(s0.x, wt0.y, at1); \
    at2 = fmaf(s0.x, wt0.z, at2); at3 = fmaf(s0.x, wt0.w, at3); \
    at0 = fmaf(s1.x, wt1.x, at0); at1 = fmaf(s1.x, wt1.y, at1); \
    at2 = fmaf(s1.x, wt1.z, at2); at3 = fmaf(s1.x, wt1.w, at3); \
    as0 = fmaf(s0.y, wv0.x, as0); as1 = fmaf(s0.y, wv0.y, as1); \
    as2 = fmaf(s0.y, wv0.z, as2); as3 = fmaf(s0.y, wv0.w, as3); \
    as0 = fmaf(s1.y, wv1.x, as0); as1 = fmaf(s1.y, wv1.y, as1); \
    as2 = fmaf(s1.y, wv1.z, as2); as3 = fmaf(s1.y, wv1.w, as3); \
    g10 = fmaf(hpa, w10.x, g10); g11 = fmaf(hpa, w10.y, g11); \
    g12 = fmaf(hpa, w10.z, g12); g13 = fmaf(hpa, w10.w, g13); \
    g10 = fmaf(hpb, w11.x, g10); g11 = fmaf(hpb, w11.y, g11); \
    g12 = fmaf(hpb, w11.z, g12); g13 = fmaf(hpb, w11.w, g13); \
    aB = fmaf(s0.z, blo(wx.x), aB); aB = fmaf(s0.x, blo(wx.y), aB); \
    aB = fmaf(s1.z, bhi(wx.x), aB); aB = fmaf(s1.x, bhi(wx.y), aB); \
    aS = fmaf(s0.w, blo(wx.z), aS); aS = fmaf(s0.y, blo(wx.w), aS); \
    aS = fmaf(s1.w, bhi(wx.z), aS); aS = fmaf(s1.y, bhi(wx.w), aS); \
  }

#define CONSUME(c, i0c) { PAIR(c, i0c, 0) PAIR(c, i0c, 1) PAIR(c, i0c, 2) PAIR(c, i0c, 3) }

#define RED2(v) { v += __shfl_xor(v, 16); v += __shfl_xor(v, 32); }

// ---------------- main persistent scan ----------------
__global__ __launch_bounds__(1024, 1) void scan8(Full f) {
  const int tid = threadIdx.x, bid = blockIdx.x;
  const int wv = tid >> 6, lane = tid & 63;
  const int q = lane >> 4, r = lane & 15;    // k-quarter in lane-high bits -> shfl reduce
  const int u = wv & 3, rg = wv >> 2;
  const int bLrow = rg * 16 + r;             // 0..63
  const int bb = bid >> 7, bj = bid & 127;
  const int ug = bj * 4 + u;                 // global unit
  const int bg = bb * 64 + bLrow;            // global batch row
  const bool lead = (q == 0);

  char* wsb = f.ws;
  const uint4* WXTP = (const uint4*)(wsb + OFF_WXTP);
  const uint4* WIHP = (const uint4*)(wsb + OFF_WIHP);
  const unsigned* FTP = (const unsigned*)(wsb + OFF_FTP);
  const uint2* W1P = (const uint2*)(wsb + OFF_W1P);
  const float* U2 = (const float*)(wsb + OFF_U2);
  const float* B2 = (const float*)(wsb + OFF_B2);
  const float2* SP2 = (const float2*)(wsb + OFF_SPA);
  float2* SP2w = (float2*)(wsb + OFF_SPA);
  float* H1f = (float*)(wsb + OFF_H1);
  float* ST = (float*)(wsb + OFF_ST);
  float* ALPHA = (float*)(wsb + OFF_AL);
  unsigned* FLG = (unsigned*)(wsb + OFF_FLG);

  float* out_logp = f.out;
  float* out_alpha = f.out + B_ * C_;
  float* out_beta = f.out + B_ * C_ + (size_t)T_ * B_ * Q_;

  // ---- LDS (~136 KB) ----
  __shared__ float WhhL[3][512][4][4];    // 98304B
  __shared__ uint4 WXL[256][4];           // 16384B
  __shared__ uint4 WihL[75][4];           //  4800B
  __shared__ unsigned FTL[75][4];         //  1200B
  __shared__ uint2 W1L[75][4];            //  2400B
  __shared__ unsigned short xcur[64][76]; //  9728B
  __shared__ float alphaL[64][26];        //  6656B (also phase-B / epilogue scratch)
  float* alphaF = &alphaL[0][0];

  // ---- stage weights into LDS (once) ----
  for (int c = 0; c < 3; ++c) {
    const float* W = (c == 0) ? f.Whh_t : (c == 1) ? f.Whh_s : f.Whh_1;
    for (int i = tid; i < 8192; i += 1024) {
      int k = i & 511, gu = i >> 9, g = gu >> 2, uu = gu & 3;
      WhhL[c][k][uu][g] = W[((size_t)(g * 512 + bj * 4 + uu)) * 512 + k];
    }
  }
  {
    int i = tid;                            // exactly 1024 entries
    int m = i >> 2, uu = i & 3;
    WXL[m][uu] = WXTP[(size_t)(bj * 4 + uu) * 256 + m];
  }
  for (int i = tid; i < 300; i += 1024) {
    int k = i >> 2, uu = i & 3;
    WihL[k][uu] = WIHP[(size_t)(bj * 4 + uu) * 75 + k];
    FTL[k][uu] = FTP[(size_t)(bj * 4 + uu) * 75 + k];
    W1L[k][uu] = W1P[(size_t)(bj * 4 + uu) * 75 + k];
  }
  for (int i = tid; i < 64 * IN_; i += 1024) {
    int rr = i / IN_, k = i - rr * IN_;
    xcur[rr][k] = tob(f.inputs[((size_t)(bb * 64 + rr) * T_) * IN_ + k]);
  }
  __syncthreads();

  // biases (indexed by ug)
  float btb0 = f.bih_t[ug] + f.bhh_t[ug];
  float btb1 = f.bih_t[512 + ug] + f.bhh_t[512 + ug];
  float btb2 = f.bih_t[1024 + ug] + f.bhh_t[1024 + ug];
  float btb3 = f.bih_t[1536 + ug] + f.bhh_t[1536 + ug];
  float bsb0 = f.bih_s[ug] + f.bhh_s[ug];
  float bsb1 = f.bih_s[512 + ug] + f.bhh_s[512 + ug];
  float bsb2 = f.bih_s[1024 + ug] + f.bhh_s[1024 + ug];
  float bsb3 = f.bih_s[1536 + ug] + f.bhh_s[1536 + ug];
  float b1b0 = f.bih_1[ug] + f.bhh_1[ug];
  float b1b1 = f.bih_1[512 + ug] + f.bhh_1[512 + ug];
  float b1b2 = f.bih_1[1024 + ug] + f.bhh_1[1024 + ug];
  float b1b3 = f.bih_1[1536 + ug] + f.bhh_1[1536 + ug];
  const float bB = f.b_s[ug] + f.b_t[ug];
  const float bS = f.b_s[ug];
  const float bT1 = f.fct_b[ug], bT2 = f.fc1_b[ug];

  float c_t = 0.f, c_s = 0.f, c1 = 0.f;
  unsigned bcount = 0;

  // pure-signaling grid barrier (sc1 state => no cache maintenance needed)
#define GBAR() do { \
    ++bcount; \
    asm volatile("s_waitcnt vmcnt(0) lgkmcnt(0)" ::: "memory"); \
    __syncthreads(); \
    if (tid == 0) \
      __hip_atomic_store(&FLG[bid * 16], bcount, __ATOMIC_RELAXED, __HIP_MEMORY_SCOPE_AGENT); \
    if (bid == 0) { \
      if (tid < 256) { \
        while (__hip_atomic_load(&FLG[tid * 16], __ATOMIC_RELAXED, __HIP_MEMORY_SCOPE_AGENT) < bcount) \
          __builtin_amdgcn_s_sleep(2); \
      } \
      __syncthreads(); \
      if (tid == 0) \
        __hip_atomic_store(&FLG[GO_IDX], bcount, __ATOMIC_RELAXED, __HIP_MEMORY_SCOPE_AGENT); \
    } \
    if (tid == 0) { \
      while (__hip_atomic_load(&FLG[GO_IDX], __ATOMIC_RELAXED, __HIP_MEMORY_SCOPE_AGENT) < bcount) \
        __builtin_amdgcn_s_sleep(2); \
    } \
    __syncthreads(); \
  } while (0)

  for (int t = 0; t < T_; ++t) {
    // ================= phase A: all k-sums vs prev state =================
    float at0 = 0, at1 = 0, at2 = 0, at3 = 0;
    float as0 = 0, as1 = 0, as2 = 0, as3 = 0;
    float g10 = 0, g11 = 0, g12 = 0, g13 = 0;
    float aB = 0, aS = 0;
    {
      Ch cA, cB;
      ldch(cA, SP2, H1f, 0, q, bg);
#pragma unroll 1
      for (int it = 0; it < 8; ++it) {
        const int i0 = it * 16;
        ldch(cB, SP2, H1f, i0 + 8, q, bg);
        CONSUME(cA, i0);
        if (it < 7) ldch(cA, SP2, H1f, i0 + 16, q, bg);
        CONSUME(cB, i0 + 8);
      }
    }
    // x-part of gates_t / gates_s (contiguous quarter of IN_)
    {
      const int kx0 = (q * IN_) >> 2, kx1 = ((q + 1) * IN_) >> 2;
      for (int k = kx0; k < kx1; ++k) {
        const float xv = __uint_as_float((unsigned)xcur[bLrow][k] << 16);
        const uint4 wi = WihL[k][u];
        at0 = fmaf(xv, blo(wi.x), at0); at1 = fmaf(xv, bhi(wi.x), at1);
        at2 = fmaf(xv, blo(wi.y), at2); at3 = fmaf(xv, bhi(wi.y), at3);
        as0 = fmaf(xv, blo(wi.z), as0); as1 = fmaf(xv, bhi(wi.z), as1);
        as2 = fmaf(xv, blo(wi.w), as2); as3 = fmaf(xv, bhi(wi.w), as3);
      }
    }
    // in-wave 4-way reduce over k-quarters
    RED2(at0) RED2(at1) RED2(at2) RED2(at3)
    RED2(as0) RED2(as1) RED2(as2) RED2(as3)
    RED2(g10) RED2(g11) RED2(g12) RED2(g13)
    RED2(aB)  RED2(aS)

    float htn = 0.f, hsn = 0.f, betav = 0.f;
    float gh0 = 0.f, gh1 = 0.f, gh2 = 0.f, gh3 = 0.f;
    if (lead) {
      const float it = sigm(at0 + btb0), ft = sigm(at1 + btb1);
      const float gt = tanhf(at2 + btb2), ot = sigm(at3 + btb3);
      c_t = ft * c_t + it * gt; htn = ot * tanhf(c_t);
      const float is = sigm(as0 + bsb0), fs = sigm(as1 + bsb1);
      const float gs = tanhf(as2 + bsb2), os = sigm(as3 + bsb3);
      c_s = fs * c_s + is * gs; hsn = os * tanhf(c_s);
      const float stv = tanhf(aS + bS);
      betav = fmaxf(aB + bB, 0.f);
      gh0 = g10 + b1b0; gh1 = g11 + b1b1; gh2 = g12 + b1b2; gh3 = g13 + b1b3;
      sta1(&ST[(size_t)bg * 512 + ug], stv);
    }
    GBAR();   // barrier 1: ST visible

    // ================= phase B: alpha softmax (128 blocks, 1 row each) =================
    if (bid < 128) {
      const int rr = bid;
      float* stl = alphaF;            // [0..511]
      float* qp = alphaF + 512;       // [25*16]
      float* qv = alphaF + 912;       // [25]
      if (tid < 512) stl[tid] = lda1(&ST[(size_t)rr * 512 + tid]);
      __syncthreads();
      if (tid < 400) {
        const int qi = tid >> 4, ks = tid & 15;
        const float* u2p = U2 + (size_t)qi * 512 + ks * 32;
        const float* sp = stl + ks * 32;
        float acc = 0.f;
        for (int j = 0; j < 32; j += 4) {
          const float4 uv = *(const float4*)(u2p + j);
          const float4 sv = *(const float4*)(sp + j);
          acc += sv.x * uv.x + sv.y * uv.y + sv.z * uv.z + sv.w * uv.w;
        }
        qp[qi * 16 + ks] = acc;
      }
      __syncthreads();
      if (tid < 25) {
        float s = B2[tid];
        for (int j = 0; j < 16; ++j) s += qp[tid * 16 + j];
        qv[tid] = s;
      }
      __syncthreads();
      if (tid < 25) {
        float m = qv[0];
        for (int i2 = 1; i2 < 25; ++i2) m = fmaxf(m, qv[i2]);
        float s = 0.f;
        for (int i2 = 0; i2 < 25; ++i2) s += expf(qv[i2] - m);
        const float a = expf(qv[tid] - m) / s;
        sta1(&ALPHA[(size_t)rr * 25 + tid], a);
        out_alpha[((size_t)t * B_ + rr) * Q_ + tid] = a;
      }
    }
    GBAR();   // barrier 2: alpha visible

    // ================= phase C: cell1 + h1*beta + tmp-next =================
    for (int i = tid; i < 64 * 25; i += 1024) {
      const int rr = i / 25, qq = i - rr * 25;
      alphaL[rr][qq] = lda1(&ALPHA[(size_t)(bb * 64 + rr) * 25 + qq]);
    }
    __syncthreads();
    float cx0 = 0, cx1 = 0, cx2 = 0, cx3 = 0;
    {
      const int g0 = (q * Q_) >> 2, g1 = ((q + 1) * Q_) >> 2;
      for (int g = g0; g < g1; ++g) {
        const float av = alphaL[bLrow][g];
#pragma unroll
        for (int j = 0; j < 3; ++j) {
          const int k = g * 3 + j;
          const float xg = __uint_as_float((unsigned)xcur[bLrow][k] << 16) * av;
          const uint2 w1v = W1L[k][u];
          cx0 = fmaf(xg, blo(w1v.x), cx0); cx1 = fmaf(xg, bhi(w1v.x), cx1);
          cx2 = fmaf(xg, blo(w1v.y), cx2); cx3 = fmaf(xg, bhi(w1v.y), cx3);
        }
      }
    }
    RED2(cx0) RED2(cx1) RED2(cx2) RED2(cx3)
    __syncthreads();
    // reload xcur <- x(t+1)
    if (t < T_ - 1) {
      for (int i = tid; i < 64 * IN_; i += 1024) {
        const int rr = i / IN_, k = i - rr * IN_;
        xcur[rr][k] = tob(f.inputs[((size_t)(bb * 64 + rr) * T_ + (t + 1)) * IN_ + k]);
      }
    }
    __syncthreads();
    float aT1 = 0.f, aT2 = 0.f;
    if (t < T_ - 1) {
      const int kx0 = (q * IN_) >> 2, kx1 = ((q + 1) * IN_) >> 2;
      for (int k = kx0; k < kx1; ++k) {
        const float xn = __uint_as_float((unsigned)xcur[bLrow][k] << 16);
        const unsigned ftv = FTL[k][u];
        aT1 = fmaf(xn, blo(ftv), aT1);
        aT2 = fmaf(xn, bhi(ftv), aT2);
      }
    }
    RED2(aT1) RED2(aT2)
    if (lead) {
      const float t1n = aT1 + bT1;
      const float t2n = aT2 + bT2;
      const float i1 = sigm(cx0 + gh0), f1 = sigm(cx1 + gh1);
      const float gg = tanhf(cx2 + gh2), o1 = sigm(cx3 + gh3);
      c1 = f1 * c1 + i1 * gg;
      const float h1g = o1 * tanhf(c1) * betav;
      sta1(&H1f[(size_t)ug * 128 + bg], h1g);
      if (t < T_ - 1) {
        const size_t e = ((size_t)ug * 128 + bg) * 2;
        sta2(&SP2w[e], make_float2(htn, hsn));
        sta2(&SP2w[e + 1], make_float2(t1n, t2n));
      }
      out_beta[((size_t)t * B_ + bg) * H_ + ug] = betav;
    }
    GBAR();   // barrier 3: SPA/H1 visible for next step
  }

  // ================= epilogue: logits + log_softmax =================
  if (bid < 128) {
    const int rr = bid;
    float* hv = alphaF;           // 512
    float* part = alphaF + 512;   // 480
    float* lg = alphaF + 1024;    // 60
    if (tid < 512) hv[tid] = lda1(&H1f[(size_t)tid * 128 + rr]);
    __syncthreads();
    if (tid < 480) {
      const int ci = tid >> 3, ks = tid & 7;
      const float* fr = f.fc_w + (size_t)ci * 512 + ks * 64;
      const float* hr = hv + ks * 64;
      float acc = 0.f;
      for (int j = 0; j < 64; j += 4) {
        const float4 fv = *(const float4*)(fr + j);
        const float4 hq = *(const float4*)(hr + j);
        acc += hq.x * fv.x + hq.y * fv.y + hq.z * fv.z + hq.w * fv.w;
      }
      part[ci * 8 + ks] = acc;
    }
    __syncthreads();
    if (tid < 60) {
      float s = f.fc_b[tid];
      for (int j = 0; j < 8; ++j) s += part[tid * 8 + j];
      lg[tid] = s;
    }
    __syncthreads();
    if (tid < 60) {
      float m = lg[0];
      for (int i2 = 1; i2 < 60; ++i2) m = fmaxf(m, lg[i2]);
      float ssum = 0.f;
      for (int i2 = 0; i2 < 60; ++i2) ssum += expf(lg[i2] - m);
      out_logp[(size_t)rr * C_ + tid] = lg[tid] - m - logf(ssum);
    }
  }
}

extern "C" void kernel_launch(void* const* d_in, const int* in_sizes, int n_in,
                              void* d_out, int out_size, void* d_ws, size_t ws_size,
                              hipStream_t stream) {
  if (ws_size < WS_BYTES) return;  // fail loudly (output stays poisoned)

  Full f;
  f.inputs = (const float*)d_in[0];
  f.Wih_t = (const float*)d_in[2];  f.Whh_t = (const float*)d_in[3];
  f.bih_t = (const float*)d_in[4];  f.bhh_t = (const float*)d_in[5];
  f.Wih_s = (const float*)d_in[6];  f.Whh_s = (const float*)d_in[7];
  f.bih_s = (const float*)d_in[8];  f.bhh_s = (const float*)d_in[9];
  f.Wih_1 = (const float*)d_in[10]; f.Whh_1 = (const float*)d_in[11];
  f.bih_1 = (const float*)d_in[12]; f.bhh_1 = (const float*)d_in[13];
  f.fc_w  = (const float*)d_in[14]; f.fc_b  = (const float*)d_in[15];
  f.fct_w = (const float*)d_in[16]; f.fct_b = (const float*)d_in[17];
  f.fc1_w = (const float*)d_in[18]; f.fc1_b = (const float*)d_in[19];
  f.fc2_w = (const float*)d_in[20]; f.fc2_b = (const float*)d_in[21];
  f.W_x_t = (const float*)d_in[22]; f.W_h_t = (const float*)d_in[23];
  f.b_t   = (const float*)d_in[24];
  f.W_x_s = (const float*)d_in[25]; f.W_h_s = (const float*)d_in[26];
  f.U_s   = (const float*)d_in[27]; f.b_s   = (const float*)d_in[28];
  f.b_us  = (const float*)d_in[29];
  f.ws = (char*)d_ws;
  f.out = (float*)d_out;

  hipLaunchKernelGGL(prep_pack, dim3(1024), dim3(256), 0, stream, f);
  hipLaunchKernelGGL(prep_state, dim3(128), dim3(512), 0, stream, f);

  void* args[] = { &f };
  hipLaunchCooperativeKernel((void*)scan8, dim3(256), dim3(1024), args, 0, stream);
}

// Round 10
// 17183.197 us; speedup vs baseline: 3.1973x; 3.1973x over previous
//
#include <hip/hip_runtime.h>
#include <math.h>

#define B_ 128
#define T_ 128
#define IN_ 75
#define H_ 512
#define C_ 60
#define Q_ 25

// ---------------- workspace layout (bytes) ----------------
constexpr size_t OFF_WXT2 = 0;         // uint2 [ug][k] bf16 {W_x_t|W_h_t, W_x_s|W_h_s}
constexpr size_t OFF_WIHP = 2097152;   // uint4 [ug][k] bf16 {it|ft, gt|ot, is|fs, gs|os}
constexpr size_t OFF_FTP  = 2711552;   // uint  [ug][k] bf16 {fct|fc1}
constexpr size_t OFF_W1P  = 2865152;   // uint2 [ug][k] bf16 {i1|f1, g1|o1}
constexpr size_t OFF_U2   = 3172352;   // float [25][512]  (U_s @ fc2_w.T)
constexpr size_t OFF_B2   = 3223552;   // float [32]
constexpr size_t OFF_SPA  = 3223680;   // float4 [k=unit][bg] {h_t,h_s,tmp1,tmp2}
constexpr size_t OFF_H1   = 4272256;   // float [k][bg]
constexpr size_t OFF_ST   = 4534400;   // float [b][j]
constexpr size_t OFF_AL   = 4796544;   // float [b][25]
constexpr size_t OFF_WHB  = 4809344;   // uint2 [(cell*512+ug)*512+k] bf16 Whh {i|f, g|o}
constexpr size_t OFF_FLG  = 11100800;  // unsigned flags, 256 x 64B; GO word on its own line
constexpr size_t WS_BYTES = 11133824;

#define GO_IDX 4112                    // own 64B line, past flag 255

struct Full {
  const float* inputs;
  const float* Wih_t; const float* Whh_t; const float* bih_t; const float* bhh_t;
  const float* Wih_s; const float* Whh_s; const float* bih_s; const float* bhh_s;
  const float* Wih_1; const float* Whh_1; const float* bih_1; const float* bhh_1;
  const float* fc_w;  const float* fc_b;
  const float* fct_w; const float* fct_b;
  const float* fc1_w; const float* fc1_b;
  const float* fc2_w; const float* fc2_b;
  const float* W_x_t; const float* W_h_t; const float* b_t;
  const float* W_x_s; const float* W_h_s; const float* U_s; const float* b_s; const float* b_us;
  char* ws; float* out;
};

__device__ __forceinline__ float sigm(float v) { return 1.f / (1.f + expf(-v)); }
__device__ __forceinline__ float blo(unsigned d) { return __uint_as_float(d << 16); }
__device__ __forceinline__ float bhi(unsigned d) { return __uint_as_float(d & 0xffff0000u); }
__device__ __forceinline__ unsigned short tob(float f) {
  unsigned u = __float_as_uint(f);
  return (unsigned short)((u + 0x7fffu + ((u >> 16) & 1u)) >> 16);
}
__device__ __forceinline__ unsigned pack2(float lo, float hi) {
  return (unsigned)tob(lo) | ((unsigned)tob(hi) << 16);
}

// ---------------- prep: pack weights ----------------
__global__ void prep_pack(Full f) {
  uint2* WXT2 = (uint2*)(f.ws + OFF_WXT2);
  uint4* WIHP = (uint4*)(f.ws + OFF_WIHP);
  unsigned* FTP = (unsigned*)(f.ws + OFF_FTP);
  uint2* W1P = (uint2*)(f.ws + OFF_W1P);
  float* U2 = (float*)(f.ws + OFF_U2);
  float* B2 = (float*)(f.ws + OFF_B2);
  uint2* WHB = (uint2*)(f.ws + OFF_WHB);
  unsigned* FLG = (unsigned*)(f.ws + OFF_FLG);
  for (int i = blockIdx.x * blockDim.x + threadIdx.x; i < 8256; i += gridDim.x * blockDim.x)
    FLG[i] = 0u;

  const size_t N1 = (size_t)512 * 512;     // WXT2
  const size_t N2 = (size_t)512 * 75;      // WIHP
  const size_t N3 = (size_t)512 * 75;      // FTP
  const size_t N4 = (size_t)512 * 75;      // W1P
  const size_t N5 = (size_t)25 * 512;      // U2
  const size_t N6 = 25;                    // B2
  const size_t N7 = (size_t)3 * 512 * 512; // WHB
  const size_t TOT = N1 + N2 + N3 + N4 + N5 + N6 + N7;
  for (size_t i = (size_t)blockIdx.x * blockDim.x + threadIdx.x; i < TOT;
       i += (size_t)gridDim.x * blockDim.x) {
    if (i < N1) {
      size_t ug = i >> 9, k = i & 511;
      uint2 v;
      v.x = pack2(f.W_x_t[k * 512 + ug], f.W_h_t[k * 512 + ug]);
      v.y = pack2(f.W_x_s[k * 512 + ug], f.W_h_s[k * 512 + ug]);
      WXT2[ug * 512 + k] = v;
    } else if (i < N1 + N2) {
      size_t j = i - N1; size_t ug = j / 75, k = j % 75;
      uint4 v;
      v.x = pack2(f.Wih_t[ug * 75 + k],          f.Wih_t[(512 + ug) * 75 + k]);
      v.y = pack2(f.Wih_t[(1024 + ug) * 75 + k], f.Wih_t[(1536 + ug) * 75 + k]);
      v.z = pack2(f.Wih_s[ug * 75 + k],          f.Wih_s[(512 + ug) * 75 + k]);
      v.w = pack2(f.Wih_s[(1024 + ug) * 75 + k], f.Wih_s[(1536 + ug) * 75 + k]);
      WIHP[ug * 75 + k] = v;
    } else if (i < N1 + N2 + N3) {
      size_t j = i - N1 - N2; size_t ug = j / 75, k = j % 75;
      FTP[ug * 75 + k] = pack2(f.fct_w[ug * 75 + k], f.fc1_w[ug * 75 + k]);
    } else if (i < N1 + N2 + N3 + N4) {
      size_t j = i - N1 - N2 - N3; size_t ug = j / 75, k = j % 75;
      uint2 v;
      v.x = pack2(f.Wih_1[ug * 75 + k],          f.Wih_1[(512 + ug) * 75 + k]);
      v.y = pack2(f.Wih_1[(1024 + ug) * 75 + k], f.Wih_1[(1536 + ug) * 75 + k]);
      W1P[ug * 75 + k] = v;
    } else if (i < N1 + N2 + N3 + N4 + N5) {
      size_t j = i - N1 - N2 - N3 - N4; size_t qi = j >> 9, col = j & 511;
      float acc = 0.f;
      for (int n = 0; n < 512; ++n) acc = fmaf(f.U_s[col * 512 + n], f.fc2_w[qi * 512 + n], acc);
      U2[qi * 512 + col] = acc;
    } else if (i < N1 + N2 + N3 + N4 + N5 + N6) {
      size_t qi = i - N1 - N2 - N3 - N4 - N5;
      float acc = f.fc2_b[qi];
      for (int n = 0; n < 512; ++n) acc = fmaf(f.b_us[n], f.fc2_w[qi * 512 + n], acc);
      B2[qi] = acc;
    } else {
      size_t e = i - N1 - N2 - N3 - N4 - N5 - N6;
      size_t c = e >> 18, rem = e & 262143, ug = rem >> 9, k = rem & 511;
      const float* W = (c == 0) ? f.Whh_t : (c == 1) ? f.Whh_s : f.Whh_1;
      uint2 v;
      v.x = pack2(W[ug * 512 + k],          W[(512 + ug) * 512 + k]);
      v.y = pack2(W[(1024 + ug) * 512 + k], W[(1536 + ug) * 512 + k]);
      WHB[e] = v;
    }
  }
}

// ---------------- prep: initial state ----------------
__global__ __launch_bounds__(512) void prep_state(Full f) {
  const int b = blockIdx.x, j = threadIdx.x;
  __shared__ float x0[77];
  if (j < IN_) x0[j] = f.inputs[(size_t)b * T_ * IN_ + j];
  __syncthreads();
  float t1 = f.fct_b[j], t2 = f.fc1_b[j];
  for (int k = 0; k < IN_; ++k) {
    t1 = fmaf(x0[k], f.fct_w[j * IN_ + k], t1);
    t2 = fmaf(x0[k], f.fc1_w[j * IN_ + k], t2);
  }
  float4* SPA4 = (float4*)(f.ws + OFF_SPA);
  SPA4[(size_t)j * 128 + b] = make_float4(0.f, 0.f, t1, t2);
  ((float*)(f.ws + OFF_H1))[(size_t)j * 128 + b] = 0.f;
}

// prefetch chunk: 4 thread-k's of state (normal cached loads)
struct Ch { float4 s[4]; float h[4]; };

#define RED3(v) { v += __shfl_xor(v, 8); v += __shfl_xor(v, 16); v += __shfl_xor(v, 32); }

// ---------------- main persistent scan: 256 blocks x 512 threads ----------------
// thread (q, bLrow): q = k-eighth, handles ALL 4 of the block's units for its k's.
__global__ __launch_bounds__(512, 2) void scan10(Full f) {
  const int tid = threadIdx.x, bid = blockIdx.x;
  const int wv = tid >> 6, lane = tid & 63;
  const int q = lane >> 3, rl = lane & 7;    // k-eighth in lane bits 3..5 -> shfl reduce
  const int bLrow = wv * 8 + rl;             // 0..63
  const int bb = bid >> 7, bj = bid & 127;
  const int ug0 = bj * 4;                    // block's first unit
  const int bg = bb * 64 + bLrow;            // global batch row
  const bool lead = (q == 0);

  char* wsb = f.ws;
  const uint2* WXT2 = (const uint2*)(wsb + OFF_WXT2);
  const uint4* WIHP = (const uint4*)(wsb + OFF_WIHP);
  const unsigned* FTP = (const unsigned*)(wsb + OFF_FTP);
  const uint2* W1P = (const uint2*)(wsb + OFF_W1P);
  const float* U2 = (const float*)(wsb + OFF_U2);
  const float* B2 = (const float*)(wsb + OFF_B2);
  const uint2* WHB = (const uint2*)(wsb + OFF_WHB);
  float4* SPA4 = (float4*)(wsb + OFF_SPA);
  float* H1f = (float*)(wsb + OFF_H1);
  float* ST = (float*)(wsb + OFF_ST);
  float* ALPHA = (float*)(wsb + OFF_AL);
  unsigned* FLG = (unsigned*)(wsb + OFF_FLG);

  float* out_logp = f.out;
  float* out_alpha = f.out + B_ * C_;
  float* out_beta = f.out + B_ * C_ + (size_t)T_ * B_ * Q_;

  // ---- LDS (~90.6 KB) ----
  __shared__ uint2 WhhL2[3][512][4];      // bf16 {i|f, g|o}          49152B
  __shared__ uint2 WXL[512][4];           // bf16 {xt|ht, xs|hs}      16384B
  __shared__ uint4 WihL[75][4];           //                           4800B
  __shared__ unsigned FTL[75][4];         //                           1200B
  __shared__ uint2 W1L[75][4];            //                           2400B
  __shared__ unsigned short xcur[64][76]; // bf16 x rows               9728B
  __shared__ float alphaL[64][26];        // alpha / scratch           6656B
  __shared__ float biasL[4][16];          //                            256B
  float* alphaF = &alphaL[0][0];

  // ---- stage weights into LDS (once) ----
  for (int i = tid; i < 6144; i += 512) {
    int c = i >> 11, rem = i & 2047, k = rem >> 2, uu = rem & 3;
    WhhL2[c][k][uu] = WHB[((size_t)(c * 512 + ug0 + uu)) * 512 + k];
  }
  for (int i = tid; i < 2048; i += 512) {
    int k = i >> 2, uu = i & 3;
    WXL[k][uu] = WXT2[(size_t)(ug0 + uu) * 512 + k];
  }
  for (int i = tid; i < 300; i += 512) {
    int k = i >> 2, uu = i & 3;
    WihL[k][uu] = WIHP[(size_t)(ug0 + uu) * 75 + k];
    FTL[k][uu] = FTP[(size_t)(ug0 + uu) * 75 + k];
    W1L[k][uu] = W1P[(size_t)(ug0 + uu) * 75 + k];
  }
  for (int i = tid; i < 64 * IN_; i += 512) {
    int rr = i / IN_, k = i - rr * IN_;
    xcur[rr][k] = tob(f.inputs[((size_t)(bb * 64 + rr) * T_) * IN_ + k]);
  }
  if (tid < 64) {
    const int uu = tid >> 4, e = tid & 15;
    const int g = ug0 + uu;
    float v;
    if (e < 4)        v = f.bih_t[e * 512 + g] + f.bhh_t[e * 512 + g];
    else if (e < 8)   v = f.bih_s[(e - 4) * 512 + g] + f.bhh_s[(e - 4) * 512 + g];
    else if (e < 12)  v = f.bih_1[(e - 8) * 512 + g] + f.bhh_1[(e - 8) * 512 + g];
    else if (e == 12) v = f.b_s[g] + f.b_t[g];       // beta bias
    else if (e == 13) v = f.b_s[g];                  // st bias
    else if (e == 14) v = f.fct_b[g];
    else              v = f.fc1_b[g];
    biasL[uu][e] = v;
  }
  __syncthreads();

  float c_t[4] = {0.f, 0.f, 0.f, 0.f};
  float c_s[4] = {0.f, 0.f, 0.f, 0.f};
  float c1[4] = {0.f, 0.f, 0.f, 0.f};
  unsigned bcount = 0;

  // r6-proven barrier: one release + one acquire per block
#define GBAR() do { \
    ++bcount; \
    __syncthreads(); \
    if (tid == 0) \
      __hip_atomic_store(&FLG[bid * 16], bcount, __ATOMIC_RELEASE, __HIP_MEMORY_SCOPE_AGENT); \
    if (bid == 0) { \
      if (tid < 256) { \
        while (__hip_atomic_load(&FLG[tid * 16], __ATOMIC_RELAXED, __HIP_MEMORY_SCOPE_AGENT) < bcount) \
          __builtin_amdgcn_s_sleep(2); \
      } \
      __syncthreads(); \
      if (tid == 0) \
        __hip_atomic_store(&FLG[GO_IDX], bcount, __ATOMIC_RELEASE, __HIP_MEMORY_SCOPE_AGENT); \
    } \
    if (tid == 0) { \
      while (__hip_atomic_load(&FLG[GO_IDX], __ATOMIC_RELAXED, __HIP_MEMORY_SCOPE_AGENT) < bcount) \
        __builtin_amdgcn_s_sleep(2); \
      (void)__hip_atomic_load(&FLG[GO_IDX], __ATOMIC_ACQUIRE, __HIP_MEMORY_SCOPE_AGENT); \
    } \
    __syncthreads(); \
  } while (0)

#define LDCH(c, i0c) { \
    _Pragma("unroll") \
    for (int ii = 0; ii < 4; ++ii) { \
      const int kk = 8 * ((i0c) + ii) + q; \
      (c).s[ii] = SPA4[(size_t)kk * 128 + bg]; \
      (c).h[ii] = H1f[(size_t)kk * 128 + bg]; \
    } }

#define CONSUME4(c, i0c) { \
    _Pragma("unroll") \
    for (int ii = 0; ii < 4; ++ii) { \
      const int kk = 8 * ((i0c) + ii) + q; \
      const float4 s4 = (c).s[ii]; \
      const float h1v = (c).h[ii]; \
      _Pragma("unroll") \
      for (int uu = 0; uu < 4; ++uu) { \
        const uint2 wt = WhhL2[0][kk][uu]; \
        at[uu][0] = fmaf(s4.x, blo(wt.x), at[uu][0]); \
        at[uu][1] = fmaf(s4.x, bhi(wt.x), at[uu][1]); \
        at[uu][2] = fmaf(s4.x, blo(wt.y), at[uu][2]); \
        at[uu][3] = fmaf(s4.x, bhi(wt.y), at[uu][3]); \
        const uint2 wvv = WhhL2[1][kk][uu]; \
        as_[uu][0] = fmaf(s4.y, blo(wvv.x), as_[uu][0]); \
        as_[uu][1] = fmaf(s4.y, bhi(wvv.x), as_[uu][1]); \
        as_[uu][2] = fmaf(s4.y, blo(wvv.y), as_[uu][2]); \
        as_[uu][3] = fmaf(s4.y, bhi(wvv.y), as_[uu][3]); \
        const uint2 w1w = WhhL2[2][kk][uu]; \
        g1a[uu][0] = fmaf(h1v, blo(w1w.x), g1a[uu][0]); \
        g1a[uu][1] = fmaf(h1v, bhi(w1w.x), g1a[uu][1]); \
        g1a[uu][2] = fmaf(h1v, blo(w1w.y), g1a[uu][2]); \
        g1a[uu][3] = fmaf(h1v, bhi(w1w.y), g1a[uu][3]); \
        const uint2 wx = WXL[kk][uu]; \
        aB[uu] = fmaf(s4.z, blo(wx.x), aB[uu]); \
        aB[uu] = fmaf(s4.x, bhi(wx.x), aB[uu]); \
        aS[uu] = fmaf(s4.w, blo(wx.y), aS[uu]); \
        aS[uu] = fmaf(s4.y, bhi(wx.y), aS[uu]); \
      } \
    } }

  for (int t = 0; t < T_; ++t) {
    // ================= phase A: all k-sums vs prev state =================
    float at[4][4] = {}; float as_[4][4] = {}; float g1a[4][4] = {};
    float aB[4] = {}, aS[4] = {};
    {
      Ch cA, cB;
      LDCH(cA, 0);
#pragma unroll 1
      for (int it2 = 0; it2 < 8; ++it2) {
        const int i0 = it2 * 8;
        LDCH(cB, i0 + 4);
        CONSUME4(cA, i0);
        if (it2 < 7) LDCH(cA, i0 + 8);
        CONSUME4(cB, i0 + 4);
      }
    }
    // x-part of gates_t / gates_s (contiguous eighth of IN_)
    {
      const int kx0 = (q * IN_) >> 3, kx1 = ((q + 1) * IN_) >> 3;
      for (int k = kx0; k < kx1; ++k) {
        const float xv = __uint_as_float((unsigned)xcur[bLrow][k] << 16);
#pragma unroll
        for (int uu = 0; uu < 4; ++uu) {
          const uint4 wi = WihL[k][uu];
          at[uu][0] = fmaf(xv, blo(wi.x), at[uu][0]);
          at[uu][1] = fmaf(xv, bhi(wi.x), at[uu][1]);
          at[uu][2] = fmaf(xv, blo(wi.y), at[uu][2]);
          at[uu][3] = fmaf(xv, bhi(wi.y), at[uu][3]);
          as_[uu][0] = fmaf(xv, blo(wi.z), as_[uu][0]);
          as_[uu][1] = fmaf(xv, bhi(wi.z), as_[uu][1]);
          as_[uu][2] = fmaf(xv, blo(wi.w), as_[uu][2]);
          as_[uu][3] = fmaf(xv, bhi(wi.w), as_[uu][3]);
        }
      }
    }
    // in-wave 8-way reduce over k-eighths
#pragma unroll
    for (int uu = 0; uu < 4; ++uu) {
      RED3(at[uu][0]) RED3(at[uu][1]) RED3(at[uu][2]) RED3(at[uu][3])
      RED3(as_[uu][0]) RED3(as_[uu][1]) RED3(as_[uu][2]) RED3(as_[uu][3])
      RED3(g1a[uu][0]) RED3(g1a[uu][1]) RED3(g1a[uu][2]) RED3(g1a[uu][3])
      RED3(aB[uu]) RED3(aS[uu])
    }

    float htn[4], hsn[4], betav[4], gh[4][4];
    if (lead) {
      float stv[4];
#pragma unroll
      for (int uu = 0; uu < 4; ++uu) {
        const float* bl = biasL[uu];
        const float iv = sigm(at[uu][0] + bl[0]), fv = sigm(at[uu][1] + bl[1]);
        const float gv = tanhf(at[uu][2] + bl[2]), ov = sigm(at[uu][3] + bl[3]);
        c_t[uu] = fv * c_t[uu] + iv * gv; htn[uu] = ov * tanhf(c_t[uu]);
        const float is = sigm(as_[uu][0] + bl[4]), fs = sigm(as_[uu][1] + bl[5]);
        const float gs = tanhf(as_[uu][2] + bl[6]), os = sigm(as_[uu][3] + bl[7]);
        c_s[uu] = fs * c_s[uu] + is * gs; hsn[uu] = os * tanhf(c_s[uu]);
        stv[uu] = tanhf(aS[uu] + bl[13]);
        betav[uu] = fmaxf(aB[uu] + bl[12], 0.f);
        gh[uu][0] = g1a[uu][0] + bl[8]; gh[uu][1] = g1a[uu][1] + bl[9];
        gh[uu][2] = g1a[uu][2] + bl[10]; gh[uu][3] = g1a[uu][3] + bl[11];
      }
      *(float4*)&ST[(size_t)bg * 512 + ug0] = make_float4(stv[0], stv[1], stv[2], stv[3]);
    }
    GBAR();   // barrier 1: ST visible

    // ================= phase B: alpha softmax (128 blocks, 1 row each) =================
    if (bid < 128) {
      const int rr = bid;
      float* stl = alphaF;            // [0..511]
      float* qp = alphaF + 512;       // [25*16]
      float* qv = alphaF + 912;       // [25]
      stl[tid] = ST[(size_t)rr * 512 + tid];
      __syncthreads();
      if (tid < 400) {
        const int qi = tid >> 4, ks = tid & 15;
        const float* u2p = U2 + (size_t)qi * 512 + ks * 32;
        const float* sp = stl + ks * 32;
        float acc = 0.f;
        for (int j = 0; j < 32; j += 4) {
          const float4 uv = *(const float4*)(u2p + j);
          const float4 sv = *(const float4*)(sp + j);
          acc += sv.x * uv.x + sv.y * uv.y + sv.z * uv.z + sv.w * uv.w;
        }
        qp[qi * 16 + ks] = acc;
      }
      __syncthreads();
      if (tid < 25) {
        float s = B2[tid];
        for (int j = 0; j < 16; ++j) s += qp[tid * 16 + j];
        qv[tid] = s;
      }
      __syncthreads();
      if (tid < 25) {
        float m = qv[0];
        for (int i2 = 1; i2 < 25; ++i2) m = fmaxf(m, qv[i2]);
        float s = 0.f;
        for (int i2 = 0; i2 < 25; ++i2) s += expf(qv[i2] - m);
        const float a = expf(qv[tid] - m) / s;
        ALPHA[(size_t)rr * 25 + tid] = a;
        out_alpha[((size_t)t * B_ + rr) * Q_ + tid] = a;
      }
    }
    GBAR();   // barrier 2: alpha visible

    // ================= phase C: cell1 + h1*beta + tmp-next =================
    for (int i = tid; i < 64 * 25; i += 512) {
      const int rr = i / 25, qq = i - rr * 25;
      alphaL[rr][qq] = ALPHA[(size_t)(bb * 64 + rr) * 25 + qq];
    }
    __syncthreads();
    float cx[4][4] = {};
    {
      const int g0 = (q * Q_) >> 3, g1 = ((q + 1) * Q_) >> 3;
      for (int g = g0; g < g1; ++g) {
        const float av = alphaL[bLrow][g];
#pragma unroll
        for (int j = 0; j < 3; ++j) {
          const int k = g * 3 + j;
          const float xg = __uint_as_float((unsigned)xcur[bLrow][k] << 16) * av;
#pragma unroll
          for (int uu = 0; uu < 4; ++uu) {
            const uint2 w1v = W1L[k][uu];
            cx[uu][0] = fmaf(xg, blo(w1v.x), cx[uu][0]);
            cx[uu][1] = fmaf(xg, bhi(w1v.x), cx[uu][1]);
            cx[uu][2] = fmaf(xg, blo(w1v.y), cx[uu][2]);
            cx[uu][3] = fmaf(xg, bhi(w1v.y), cx[uu][3]);
          }
        }
      }
    }
#pragma unroll
    for (int uu = 0; uu < 4; ++uu) {
      RED3(cx[uu][0]) RED3(cx[uu][1]) RED3(cx[uu][2]) RED3(cx[uu][3])
    }
    __syncthreads();
    // reload xcur <- x(t+1)
    if (t < T_ - 1) {
      for (int i = tid; i < 64 * IN_; i += 512) {
        const int rr = i / IN_, k = i - rr * IN_;
        xcur[rr][k] = tob(f.inputs[((size_t)(bb * 64 + rr) * T_ + (t + 1)) * IN_ + k]);
      }
    }
    __syncthreads();
    float aT1[4] = {}, aT2[4] = {};
    if (t < T_ - 1) {
      const int kx0 = (q * IN_) >> 3, kx1 = ((q + 1) * IN_) >> 3;
      for (int k = kx0; k < kx1; ++k) {
        const float xn = __uint_as_float((unsigned)xcur[bLrow][k] << 16);
#pragma unroll
        for (int uu = 0; uu < 4; ++uu) {
          const unsigned ftv = FTL[k][uu];
          aT1[uu] = fmaf(xn, blo(ftv), aT1[uu]);
          aT2[uu] = fmaf(xn, bhi(ftv), aT2[uu]);
        }
      }
    }
#pragma unroll
    for (int uu = 0; uu < 4; ++uu) { RED3(aT1[uu]) RED3(aT2[uu]) }
    if (lead) {
      float h1g[4];
#pragma unroll
      for (int uu = 0; uu < 4; ++uu) {
        const float* bl = biasL[uu];
        const float t1n = aT1[uu] + bl[14];
        const float t2n = aT2[uu] + bl[15];
        const float i1 = sigm(cx[uu][0] + gh[uu][0]), f1 = sigm(cx[uu][1] + gh[uu][1]);
        const float gg = tanhf(cx[uu][2] + gh[uu][2]), o1 = sigm(cx[uu][3] + gh[uu][3]);
        c1[uu] = f1 * c1[uu] + i1 * gg;
        h1g[uu] = o1 * tanhf(c1[uu]) * betav[uu];
        H1f[(size_t)(ug0 + uu) * 128 + bg] = h1g[uu];
        if (t < T_ - 1)
          SPA4[(size_t)(ug0 + uu) * 128 + bg] = make_float4(htn[uu], hsn[uu], t1n, t2n);
      }
      *(float4*)&out_beta[((size_t)t * B_ + bg) * H_ + ug0] =
          make_float4(betav[0], betav[1], betav[2], betav[3]);
    }
    GBAR();   // barrier 3: SPA/H1 visible for next step
  }

  // ================= epilogue: logits + log_softmax =================
  if (bid < 128) {
    const int rr = bid;
    float* hv = alphaF;           // 512
    float* part = alphaF + 512;   // 480
    float* lg = alphaF + 1024;    // 60
    hv[tid] = H1f[(size_t)tid * 128 + rr];
    __syncthreads();
    if (tid < 480) {
      const int ci = tid >> 3, ks = tid & 7;
      const float* fr = f.fc_w + (size_t)ci * 512 + ks * 64;
      const float* hr = hv + ks * 64;
      float acc = 0.f;
      for (int j = 0; j < 64; j += 4) {
        const float4 fv = *(const float4*)(fr + j);
        const float4 hq = *(const float4*)(hr + j);
        acc += hq.x * fv.x + hq.y * fv.y + hq.z * fv.z + hq.w * fv.w;
      }
      part[ci * 8 + ks] = acc;
    }
    __syncthreads();
    if (tid < 60) {
      float s = f.fc_b[tid];
      for (int j = 0; j < 8; ++j) s += part[tid * 8 + j];
      lg[tid] = s;
    }
    __syncthreads();
    if (tid < 60) {
      float m = lg[0];
      for (int i2 = 1; i2 < 60; ++i2) m = fmaxf(m, lg[i2]);
      float ssum = 0.f;
      for (int i2 = 0; i2 < 60; ++i2) ssum += expf(lg[i2] - m);
      out_logp[(size_t)rr * C_ + tid] = lg[tid] - m - logf(ssum);
    }
  }
}

extern "C" void kernel_launch(void* const* d_in, const int* in_sizes, int n_in,
                              void* d_out, int out_size, void* d_ws, size_t ws_size,
                              hipStream_t stream) {
  if (ws_size < WS_BYTES) return;  // fail loudly (output stays poisoned)

  Full f;
  f.inputs = (const float*)d_in[0];
  f.Wih_t = (const float*)d_in[2];  f.Whh_t = (const float*)d_in[3];
  f.bih_t = (const float*)d_in[4];  f.bhh_t = (const float*)d_in[5];
  f.Wih_s = (const float*)d_in[6];  f.Whh_s = (const float*)d_in[7];
  f.bih_s = (const float*)d_in[8];  f.bhh_s = (const float*)d_in[9];
  f.Wih_1 = (const float*)d_in[10]; f.Whh_1 = (const float*)d_in[11];
  f.bih_1 = (const float*)d_in[12]; f.bhh_1 = (const float*)d_in[13];
  f.fc_w  = (const float*)d_in[14]; f.fc_b  = (const float*)d_in[15];
  f.fct_w = (const float*)d_in[16]; f.fct_b = (const float*)d_in[17];
  f.fc1_w = (const float*)d_in[18]; f.fc1_b = (const float*)d_in[19];
  f.fc2_w = (const float*)d_in[20]; f.fc2_b = (const float*)d_in[21];
  f.W_x_t = (const float*)d_in[22]; f.W_h_t = (const float*)d_in[23];
  f.b_t   = (const float*)d_in[24];
  f.W_x_s = (const float*)d_in[25]; f.W_h_s = (const float*)d_in[26];
  f.U_s   = (const float*)d_in[27]; f.b_s   = (const float*)d_in[28];
  f.b_us  = (const float*)d_in[29];
  f.ws = (char*)d_ws;
  f.out = (float*)d_out;

  hipLaunchKernelGGL(prep_pack, dim3(1024), dim3(256), 0, stream, f);
  hipLaunchKernelGGL(prep_state, dim3(128), dim3(512), 0, stream, f);

  void* args[] = { &f };
  hipLaunchCooperativeKernel((void*)scan10, dim3(256), dim3(512), args, 0, stream);
}

// Round 11
// 11716.317 us; speedup vs baseline: 4.6892x; 1.4666x over previous
//
#include <hip/hip_runtime.h>
#include <math.h>

#define B_ 128
#define T_ 128
#define IN_ 75
#define H_ 512
#define C_ 60
#define Q_ 25

// ---------------- workspace layout (bytes) ----------------
constexpr size_t OFF_WHHP = 0;          // uint4 [(c*256+k2)*512+u] f16 gate-pairs {i,f,g,o}
constexpr size_t OFF_WIHP = 6291456;    // uint4 [(c*38+k2)*512+u]  f16 gate-pairs (x-part)
constexpr size_t OFF_WXHP = 7225344;    // uint  [(w*256+k2)*512+u] f16 pairs, w: Wxt,Wht,Wxs,Whs
constexpr size_t OFF_FT2P = 9322496;    // uint  [(c*38+k2)*512+u]  f16 pairs, c: fct,fc1
constexpr size_t OFF_U2   = 9478144;    // float [25][512] (U_s @ fc2_w.T)
constexpr size_t OFF_B2   = 9529344;    // float [32]
constexpr size_t OFF_ST8  = 9529472;    // 9 x uint[256][128] state buffers (f16 pairs along k)
//   HT2[2] @ +0,+131072 ; HS2[2] @ +262144,+393216 ; T12[2] @ +524288,+655360 ;
//   T22[2] @ +786432,+917504 ; H12 @ +1048576
constexpr size_t OFF_BETA = 10709120;   // float [512][128]
constexpr size_t OFF_QP   = 10971264;   // float [32][128][25]
constexpr size_t OFF_FLG  = 11380864;   // 256 x 64B flags + GO line
constexpr size_t WS_BYTES = 11397376;

#define GO_IDX 4112

struct Full {
  const float* inputs;
  const float* Wih_t; const float* Whh_t; const float* bih_t; const float* bhh_t;
  const float* Wih_s; const float* Whh_s; const float* bih_s; const float* bhh_s;
  const float* Wih_1; const float* Whh_1; const float* bih_1; const float* bhh_1;
  const float* fc_w;  const float* fc_b;
  const float* fct_w; const float* fct_b;
  const float* fc1_w; const float* fc1_b;
  const float* fc2_w; const float* fc2_b;
  const float* W_x_t; const float* W_h_t; const float* b_t;
  const float* W_x_s; const float* W_h_s; const float* U_s; const float* b_s; const float* b_us;
  char* ws; float* out;
};

typedef _Float16 h2t __attribute__((ext_vector_type(2)));
union U32H { unsigned u; h2t h; unsigned short s[2]; };

__device__ __forceinline__ float sigm(float v) { return 1.f / (1.f + expf(-v)); }
__device__ __forceinline__ float dot2(unsigned a, unsigned b, float c) {
#if __has_builtin(__builtin_amdgcn_fdot2)
  U32H A, B; A.u = a; B.u = b;
  return __builtin_amdgcn_fdot2(A.h, B.h, c, false);
#else
  U32H A, B; A.u = a; B.u = b;
  return fmaf((float)A.h.x, (float)B.h.x, fmaf((float)A.h.y, (float)B.h.y, c));
#endif
}
__device__ __forceinline__ unsigned pack2h(float a, float b) {
  U32H r; r.h.x = (_Float16)a; r.h.y = (_Float16)b; return r.u;
}
__device__ __forceinline__ unsigned short f2h(float a) {
  U32H r; r.u = 0; r.h.x = (_Float16)a; return r.s[0];
}
__device__ __forceinline__ unsigned packss(unsigned short lo, unsigned short hi) {
  return (unsigned)lo | ((unsigned)hi << 16);
}
__device__ __forceinline__ float hlo(unsigned v) { U32H r; r.u = v; return (float)r.h.x; }
__device__ __forceinline__ float hhi(unsigned v) { U32H r; r.u = v; return (float)r.h.y; }

// ---------------- prep: pack weights (f16 pairs along k) ----------------
__global__ void prep_pack(Full f) {
  uint4* WHHP = (uint4*)(f.ws + OFF_WHHP);
  uint4* WIHP = (uint4*)(f.ws + OFF_WIHP);
  unsigned* WXHP = (unsigned*)(f.ws + OFF_WXHP);
  unsigned* FT2P = (unsigned*)(f.ws + OFF_FT2P);
  float* U2 = (float*)(f.ws + OFF_U2);
  float* B2 = (float*)(f.ws + OFF_B2);
  unsigned* FLG = (unsigned*)(f.ws + OFF_FLG);
  for (int i = blockIdx.x * blockDim.x + threadIdx.x; i < 4128; i += gridDim.x * blockDim.x)
    FLG[i] = 0u;

  const size_t N1 = (size_t)3 * 256 * 512;   // WHHP uint4
  const size_t N2 = (size_t)3 * 38 * 512;    // WIHP uint4
  const size_t N3 = (size_t)4 * 256 * 512;   // WXHP uint
  const size_t N4 = (size_t)2 * 38 * 512;    // FT2P uint
  const size_t N5 = (size_t)25 * 512;        // U2
  const size_t N6 = 25;                      // B2
  const size_t TOT = N1 + N2 + N3 + N4 + N5 + N6;
  for (size_t i = (size_t)blockIdx.x * blockDim.x + threadIdx.x; i < TOT;
       i += (size_t)gridDim.x * blockDim.x) {
    if (i < N1) {
      size_t c = i / 131072, r = i % 131072, k2 = r >> 9, u = r & 511;
      const float* W = (c == 0) ? f.Whh_t : (c == 1) ? f.Whh_s : f.Whh_1;
      uint4 v;
      v.x = pack2h(W[(0 * 512 + u) * 512 + 2 * k2], W[(0 * 512 + u) * 512 + 2 * k2 + 1]);
      v.y = pack2h(W[(1 * 512 + u) * 512 + 2 * k2], W[(1 * 512 + u) * 512 + 2 * k2 + 1]);
      v.z = pack2h(W[(2 * 512 + u) * 512 + 2 * k2], W[(2 * 512 + u) * 512 + 2 * k2 + 1]);
      v.w = pack2h(W[(3 * 512 + u) * 512 + 2 * k2], W[(3 * 512 + u) * 512 + 2 * k2 + 1]);
      WHHP[i] = v;
    } else if (i < N1 + N2) {
      size_t e = i - N1; size_t c = e / 19456, r = e % 19456, k2 = r >> 9, u = r & 511;
      const float* W = (c == 0) ? f.Wih_t : (c == 1) ? f.Wih_s : f.Wih_1;
      int k = 2 * (int)k2;
      uint4 v;
#pragma unroll
      for (int g = 0; g < 4; ++g) {
        float a = (k < 75) ? W[(g * 512 + u) * 75 + k] : 0.f;
        float b = (k + 1 < 75) ? W[(g * 512 + u) * 75 + k + 1] : 0.f;
        (&v.x)[g] = pack2h(a, b);
      }
      WIHP[e] = v;
    } else if (i < N1 + N2 + N3) {
      size_t e = i - N1 - N2; size_t w = e / 131072, r = e % 131072, k2 = r >> 9, u = r & 511;
      const float* W = (w == 0) ? f.W_x_t : (w == 1) ? f.W_h_t : (w == 2) ? f.W_x_s : f.W_h_s;
      WXHP[e] = pack2h(W[2 * k2 * 512 + u], W[(2 * k2 + 1) * 512 + u]);
    } else if (i < N1 + N2 + N3 + N4) {
      size_t e = i - N1 - N2 - N3; size_t c = e / 19456, r = e % 19456, k2 = r >> 9, u = r & 511;
      const float* W = c ? f.fc1_w : f.fct_w;
      int k = 2 * (int)k2;
      float a = (k < 75) ? W[u * 75 + k] : 0.f;
      float b = (k + 1 < 75) ? W[u * 75 + k + 1] : 0.f;
      FT2P[e] = pack2h(a, b);
    } else if (i < N1 + N2 + N3 + N4 + N5) {
      size_t e = i - N1 - N2 - N3 - N4; size_t qi = e >> 9, u = e & 511;
      float acc = 0.f;
      for (int n = 0; n < 512; ++n) acc = fmaf(f.U_s[u * 512 + n], f.fc2_w[qi * 512 + n], acc);
      U2[qi * 512 + u] = acc;
    } else {
      size_t qi = i - N1 - N2 - N3 - N4 - N5;
      float acc = f.fc2_b[qi];
      for (int n = 0; n < 512; ++n) acc = fmaf(f.b_us[n], f.fc2_w[qi * 512 + n], acc);
      B2[qi] = acc;
    }
  }
}

// ---------------- prep: initial state ----------------
__global__ __launch_bounds__(512) void prep_state(Full f) {
  const int b = blockIdx.x, j = threadIdx.x;
  __shared__ float x0[77];
  __shared__ float t1L[512], t2L[512];
  if (j < IN_) x0[j] = f.inputs[(size_t)b * T_ * IN_ + j];
  __syncthreads();
  float t1 = f.fct_b[j], t2 = f.fc1_b[j];
  for (int k = 0; k < IN_; ++k) {
    t1 = fmaf(x0[k], f.fct_w[j * IN_ + k], t1);
    t2 = fmaf(x0[k], f.fc1_w[j * IN_ + k], t2);
  }
  t1L[j] = t1; t2L[j] = t2;
  __syncthreads();
  unsigned* S = (unsigned*)(f.ws + OFF_ST8);
  if (j < 256) {
    S[0 * 32768 + j * 128 + b] = 0u;          // HT2[0]
    S[2 * 32768 + j * 128 + b] = 0u;          // HS2[0]
    S[8 * 32768 + j * 128 + b] = 0u;          // H12
    S[4 * 32768 + j * 128 + b] = pack2h(t1L[2 * j], t1L[2 * j + 1]);  // T12[0]
    S[6 * 32768 + j * 128 + b] = pack2h(t2L[2 * j], t2L[2 * j + 1]);  // T22[0]
  }
}

// ---------------- main persistent scan ----------------
__global__ __launch_bounds__(512, 4) void scan11(Full f) {
  const int tid = threadIdx.x, bid = blockIdx.x;
  const int lane = tid & 63, wave = tid >> 6;

  char* wsb = f.ws;
  const uint4* WHHP = (const uint4*)(wsb + OFF_WHHP);
  const uint4* WIHP = (const uint4*)(wsb + OFF_WIHP);
  const unsigned* WXHP = (const unsigned*)(wsb + OFF_WXHP);
  const unsigned* FT2P = (const unsigned*)(wsb + OFF_FT2P);
  const float* U2 = (const float*)(wsb + OFF_U2);
  const float* B2 = (const float*)(wsb + OFF_B2);
  unsigned* SB = (unsigned*)(wsb + OFF_ST8);   // 9 x 32768-uint buffers
  float* BETA = (float*)(wsb + OFF_BETA);
  float* QPART = (float*)(wsb + OFF_QP);
  unsigned* FLG = (unsigned*)(wsb + OFF_FLG);

  float* out_logp = f.out;
  float* out_alpha = f.out + B_ * C_;
  float* out_beta = f.out + B_ * C_ + (size_t)T_ * B_ * Q_;

  __shared__ __align__(16) char lds[73728];

  unsigned bcount = 0;
#define GBAR() do { \
    ++bcount; \
    __syncthreads(); \
    if (tid == 0) \
      __hip_atomic_store(&FLG[bid * 16], bcount, __ATOMIC_RELEASE, __HIP_MEMORY_SCOPE_AGENT); \
    if (bid == 0) { \
      if (tid < 256) { \
        while (__hip_atomic_load(&FLG[tid * 16], __ATOMIC_RELAXED, __HIP_MEMORY_SCOPE_AGENT) < bcount) \
          __builtin_amdgcn_s_sleep(2); \
      } \
      __syncthreads(); \
      if (tid == 0) \
        __hip_atomic_store(&FLG[GO_IDX], bcount, __ATOMIC_RELEASE, __HIP_MEMORY_SCOPE_AGENT); \
    } \
    if (tid == 0) { \
      while (__hip_atomic_load(&FLG[GO_IDX], __ATOMIC_RELAXED, __HIP_MEMORY_SCOPE_AGENT) < bcount) \
        __builtin_amdgcn_s_sleep(2); \
      (void)__hip_atomic_load(&FLG[GO_IDX], __ATOMIC_ACQUIRE, __HIP_MEMORY_SCOPE_AGENT); \
    } \
    __syncthreads(); \
  } while (0)

  if (bid < 192) {
    // ================= cell-GEMM groups: T (0-63), S (64-127), 1 (128-191) =================
    const int grp = bid >> 6;
    const int u0 = (bid & 63) * 8;
    const int u = u0 + wave;
    const int b0 = lane, b1 = lane + 64;

    uint4* WhhL = (uint4*)lds;                       // [256][8]   32768
    uint4* WihL = (uint4*)(lds + 32768);             // [38][8]     4864
    unsigned* xL = (unsigned*)(lds + 37632);         // [38][128]  19456
    unsigned short* hstg = (unsigned short*)(lds + 57088); // [8][128]  2048
    float* qa = (float*)(lds + 59136);               // [128][25]  12800 (grp2)
    float* biasLo = (float*)(lds + 71936);           // [8][4]       128

    for (int i = tid; i < 2048; i += 512) {
      int k2 = i >> 3, uu = i & 7;
      WhhL[k2 * 8 + uu] = WHHP[((size_t)grp * 256 + k2) * 512 + u0 + uu];
    }
    for (int i = tid; i < 304; i += 512) {
      int k2 = i >> 3, uu = i & 7;
      WihL[k2 * 8 + uu] = WIHP[((size_t)grp * 38 + k2) * 512 + u0 + uu];
    }
    if (tid < 32) {
      int uu = tid >> 2, g = tid & 3;
      const float* bi = (grp == 0) ? f.bih_t : (grp == 1) ? f.bih_s : f.bih_1;
      const float* bh = (grp == 0) ? f.bhh_t : (grp == 1) ? f.bhh_s : f.bhh_1;
      biasLo[uu * 4 + g] = bi[g * 512 + u0 + uu] + bh[g * 512 + u0 + uu];
    }
    __syncthreads();

    float cc0 = 0.f, cc1 = 0.f;          // c_t / c_s / c1 for rows b0,b1
    float gh0 = 0, gh1 = 0, gh2 = 0, gh3 = 0, gh4 = 0, gh5 = 0, gh6 = 0, gh7 = 0;

    for (int t = 0; t < T_; ++t) {
      const int cur = t & 1;
      // stage x(t) as f16 pairs
      for (int i = tid; i < 38 * 128; i += 512) {
        int k2 = i >> 7, b = i & 127;
        float xa = f.inputs[((size_t)b * T_ + t) * IN_ + 2 * k2];
        float xb = (2 * k2 + 1 < IN_) ? f.inputs[((size_t)b * T_ + t) * IN_ + 2 * k2 + 1] : 0.f;
        xL[k2 * 128 + b] = pack2h(xa, xb);
      }
      __syncthreads();

      const unsigned* Sr = (grp == 0) ? (SB + (size_t)cur * 32768)
                        : (grp == 1) ? (SB + (size_t)(2 + cur) * 32768)
                                     : (SB + (size_t)8 * 32768);
      float a0 = 0, a1 = 0, a2 = 0, a3 = 0, a4 = 0, a5 = 0, a6 = 0, a7 = 0;
#pragma unroll 4
      for (int k2 = 0; k2 < 256; ++k2) {
        const unsigned s0 = Sr[k2 * 128 + b0];
        const unsigned s1 = Sr[k2 * 128 + b1];
        const uint4 w = WhhL[k2 * 8 + wave];
        a0 = dot2(s0, w.x, a0); a1 = dot2(s0, w.y, a1);
        a2 = dot2(s0, w.z, a2); a3 = dot2(s0, w.w, a3);
        a4 = dot2(s1, w.x, a4); a5 = dot2(s1, w.y, a5);
        a6 = dot2(s1, w.z, a6); a7 = dot2(s1, w.w, a7);
      }
      if (grp < 2) {
#pragma unroll 2
        for (int k2 = 0; k2 < 38; ++k2) {
          const unsigned x0p = xL[k2 * 128 + b0];
          const unsigned x1p = xL[k2 * 128 + b1];
          const uint4 wi = WihL[k2 * 8 + wave];
          a0 = dot2(x0p, wi.x, a0); a1 = dot2(x0p, wi.y, a1);
          a2 = dot2(x0p, wi.z, a2); a3 = dot2(x0p, wi.w, a3);
          a4 = dot2(x1p, wi.x, a4); a5 = dot2(x1p, wi.y, a5);
          a6 = dot2(x1p, wi.z, a6); a7 = dot2(x1p, wi.w, a7);
        }
        const float* bl = &biasLo[wave * 4];
        {
          const float iv = sigm(a0 + bl[0]), fv = sigm(a1 + bl[1]);
          const float gv = tanhf(a2 + bl[2]), ov = sigm(a3 + bl[3]);
          cc0 = fv * cc0 + iv * gv;
          hstg[wave * 128 + b0] = f2h(ov * tanhf(cc0));
        }
        {
          const float iv = sigm(a4 + bl[0]), fv = sigm(a5 + bl[1]);
          const float gv = tanhf(a6 + bl[2]), ov = sigm(a7 + bl[3]);
          cc1 = fv * cc1 + iv * gv;
          hstg[wave * 128 + b1] = f2h(ov * tanhf(cc1));
        }
        __syncthreads();
        unsigned* Sw = (grp == 0) ? (SB + (size_t)(cur ^ 1) * 32768)
                                  : (SB + (size_t)(2 + (cur ^ 1)) * 32768);
        {
          int p = tid >> 7, b = tid & 127;
          Sw[(u0 / 2 + p) * 128 + b] =
              packss(hstg[(2 * p) * 128 + b], hstg[(2 * p + 1) * 128 + b]);
        }
      } else {
        const float* bl = &biasLo[wave * 4];
        gh0 = a0 + bl[0]; gh1 = a1 + bl[1]; gh2 = a2 + bl[2]; gh3 = a3 + bl[3];
        gh4 = a4 + bl[0]; gh5 = a5 + bl[1]; gh6 = a6 + bl[2]; gh7 = a7 + bl[3];
      }
      GBAR();   // barrier 1

      if (grp == 2) {
        // q-sum (fixed order, deterministic) + softmax
        for (int i = tid; i < 3200; i += 512) {
          int b = i / 25, qi = i - b * 25;
          float s = B2[qi];
#pragma unroll 8
          for (int s32 = 0; s32 < 32; ++s32) s += QPART[((size_t)s32 * 128 + b) * 25 + qi];
          qa[i] = s;
        }
        __syncthreads();
        if (tid < 128) {
          float* row = &qa[tid * 25];
          float m = row[0];
          for (int i2 = 1; i2 < 25; ++i2) m = fmaxf(m, row[i2]);
          float s = 0.f;
          for (int i2 = 0; i2 < 25; ++i2) { row[i2] = expf(row[i2] - m); s += row[i2]; }
          const float inv = 1.f / s;
          for (int i2 = 0; i2 < 25; ++i2) row[i2] *= inv;
        }
        __syncthreads();
        if (bid == 128) {
          for (int i = tid; i < 3200; i += 512) {
            int b = i / 25, qi = i - b * 25;
            out_alpha[((size_t)t * B_ + b) * Q_ + qi] = qa[i];
          }
        }
        // x_gated @ Wih_1 (K=75, fp32)
        float cx0 = 0, cx1 = 0, cx2 = 0, cx3 = 0, cx4 = 0, cx5 = 0, cx6 = 0, cx7 = 0;
        const float* a0r = &qa[b0 * 25];
        const float* a1r = &qa[b1 * 25];
        for (int k2 = 0; k2 < 38; ++k2) {
          const uint4 wq = WihL[k2 * 8 + wave];
          const unsigned x0p = xL[k2 * 128 + b0];
          const unsigned x1p = xL[k2 * 128 + b1];
          const int k = 2 * k2;
          const int ai0 = k / 3;
          const int ai1 = (k + 1 < IN_) ? (k + 1) / 3 : 24;
          const float xg0e = hlo(x0p) * a0r[ai0];
          const float xg0o = hhi(x0p) * a0r[ai1];
          const float xg1e = hlo(x1p) * a1r[ai0];
          const float xg1o = hhi(x1p) * a1r[ai1];
          cx0 = fmaf(xg0e, hlo(wq.x), cx0); cx0 = fmaf(xg0o, hhi(wq.x), cx0);
          cx1 = fmaf(xg0e, hlo(wq.y), cx1); cx1 = fmaf(xg0o, hhi(wq.y), cx1);
          cx2 = fmaf(xg0e, hlo(wq.z), cx2); cx2 = fmaf(xg0o, hhi(wq.z), cx2);
          cx3 = fmaf(xg0e, hlo(wq.w), cx3); cx3 = fmaf(xg0o, hhi(wq.w), cx3);
          cx4 = fmaf(xg1e, hlo(wq.x), cx4); cx4 = fmaf(xg1o, hhi(wq.x), cx4);
          cx5 = fmaf(xg1e, hlo(wq.y), cx5); cx5 = fmaf(xg1o, hhi(wq.y), cx5);
          cx6 = fmaf(xg1e, hlo(wq.z), cx6); cx6 = fmaf(xg1o, hhi(wq.z), cx6);
          cx7 = fmaf(xg1e, hlo(wq.w), cx7); cx7 = fmaf(xg1o, hhi(wq.w), cx7);
        }
        const float be0 = BETA[(size_t)u * 128 + b0];
        const float be1 = BETA[(size_t)u * 128 + b1];
        {
          const float i1 = sigm(cx0 + gh0), f1 = sigm(cx1 + gh1);
          const float g1 = tanhf(cx2 + gh2), o1 = sigm(cx3 + gh3);
          cc0 = f1 * cc0 + i1 * g1;
          hstg[wave * 128 + b0] = f2h(o1 * tanhf(cc0) * be0);
        }
        {
          const float i1 = sigm(cx4 + gh4), f1 = sigm(cx5 + gh5);
          const float g1 = tanhf(cx6 + gh6), o1 = sigm(cx7 + gh7);
          cc1 = f1 * cc1 + i1 * g1;
          hstg[wave * 128 + b1] = f2h(o1 * tanhf(cc1) * be1);
        }
        __syncthreads();
        {
          int p = tid >> 7, b = tid & 127;
          SB[(size_t)8 * 32768 + (u0 / 2 + p) * 128 + b] =
              packss(hstg[(2 * p) * 128 + b], hstg[(2 * p + 1) * 128 + b]);
        }
      }
      GBAR();   // barrier 2
    }
  } else {
    // ================= K=1024 groups: B (192-223, beta+tmp1) / Q (224-255, st+q+tmp2) =================
    const bool isQ = (bid >= 224);
    const int u0 = (isQ ? (bid - 224) : (bid - 192)) * 16;
    const int ub = tid >> 5, bs = tid & 31;

    unsigned* WxL = (unsigned*)lds;                  // [256][16]  16384
    unsigned* WhL = (unsigned*)(lds + 16384);        // [256][16]  16384
    unsigned* fcL = (unsigned*)(lds + 32768);        // [38][16]    2432
    unsigned* xnL = (unsigned*)(lds + 35200);        // [38][128]  19456
    unsigned short* tstg = (unsigned short*)(lds + 54656); // [16][128] 4096
    float* stL = (float*)(lds + 58752);              // [16][128]   8192 (Q only)
    float* biasB = (float*)(lds + 66944);            // [16][2]      128

    for (int i = tid; i < 4096; i += 512) {
      int k2 = i >> 4, uu = i & 15;
      WxL[k2 * 16 + uu] = WXHP[((size_t)(isQ ? 2 : 0) * 256 + k2) * 512 + u0 + uu];
      WhL[k2 * 16 + uu] = WXHP[((size_t)(isQ ? 3 : 1) * 256 + k2) * 512 + u0 + uu];
    }
    for (int i = tid; i < 608; i += 512) {
      int k2 = i >> 4, uu = i & 15;
      fcL[k2 * 16 + uu] = FT2P[((size_t)(isQ ? 1 : 0) * 38 + k2) * 512 + u0 + uu];
    }
    if (tid < 16) {
      int g = u0 + tid;
      biasB[tid * 2] = isQ ? f.b_s[g] : (f.b_s[g] + f.b_t[g]);
      biasB[tid * 2 + 1] = isQ ? f.fc1_b[g] : f.fct_b[g];
    }
    __syncthreads();

    for (int t = 0; t < T_; ++t) {
      const int cur = t & 1;
      if (t < T_ - 1) {
        for (int i = tid; i < 38 * 128; i += 512) {
          int k2 = i >> 7, b = i & 127;
          float xa = f.inputs[((size_t)b * T_ + t + 1) * IN_ + 2 * k2];
          float xb = (2 * k2 + 1 < IN_) ? f.inputs[((size_t)b * T_ + t + 1) * IN_ + 2 * k2 + 1] : 0.f;
          xnL[k2 * 128 + b] = pack2h(xa, xb);
        }
      }
      __syncthreads();

      const unsigned* TA = SB + (size_t)((isQ ? 6 : 4) + cur) * 32768;   // T22/T12 [cur]
      const unsigned* SA = SB + (size_t)((isQ ? 2 : 0) + cur) * 32768;   // HS2/HT2 [cur]
      float ac0 = 0, ac1 = 0, ac2 = 0, ac3 = 0;
#pragma unroll 2
      for (int k2 = 0; k2 < 256; ++k2) {
        const unsigned wx = WxL[k2 * 16 + ub];
        const unsigned wh = WhL[k2 * 16 + ub];
        ac0 = dot2(TA[k2 * 128 + bs],      wx, ac0);
        ac1 = dot2(TA[k2 * 128 + bs + 32], wx, ac1);
        ac2 = dot2(TA[k2 * 128 + bs + 64], wx, ac2);
        ac3 = dot2(TA[k2 * 128 + bs + 96], wx, ac3);
        ac0 = dot2(SA[k2 * 128 + bs],      wh, ac0);
        ac1 = dot2(SA[k2 * 128 + bs + 32], wh, ac1);
        ac2 = dot2(SA[k2 * 128 + bs + 64], wh, ac2);
        ac3 = dot2(SA[k2 * 128 + bs + 96], wh, ac3);
      }
      const float bb0 = biasB[ub * 2];
      if (!isQ) {
        float bv;
        bv = fmaxf(ac0 + bb0, 0.f); BETA[(size_t)(u0 + ub) * 128 + bs]      = bv;
        out_beta[((size_t)t * B_ + bs) * H_ + u0 + ub] = bv;
        bv = fmaxf(ac1 + bb0, 0.f); BETA[(size_t)(u0 + ub) * 128 + bs + 32] = bv;
        out_beta[((size_t)t * B_ + bs + 32) * H_ + u0 + ub] = bv;
        bv = fmaxf(ac2 + bb0, 0.f); BETA[(size_t)(u0 + ub) * 128 + bs + 64] = bv;
        out_beta[((size_t)t * B_ + bs + 64) * H_ + u0 + ub] = bv;
        bv = fmaxf(ac3 + bb0, 0.f); BETA[(size_t)(u0 + ub) * 128 + bs + 96] = bv;
        out_beta[((size_t)t * B_ + bs + 96) * H_ + u0 + ub] = bv;
      } else {
        stL[ub * 128 + bs]      = tanhf(ac0 + bb0);
        stL[ub * 128 + bs + 32] = tanhf(ac1 + bb0);
        stL[ub * 128 + bs + 64] = tanhf(ac2 + bb0);
        stL[ub * 128 + bs + 96] = tanhf(ac3 + bb0);
      }
      // tmp-next (x_{t+1} @ fct/fc1)
      float tn0 = 0, tn1 = 0, tn2 = 0, tn3 = 0;
#pragma unroll 2
      for (int k2 = 0; k2 < 38; ++k2) {
        const unsigned fc = fcL[k2 * 16 + ub];
        tn0 = dot2(xnL[k2 * 128 + bs],      fc, tn0);
        tn1 = dot2(xnL[k2 * 128 + bs + 32], fc, tn1);
        tn2 = dot2(xnL[k2 * 128 + bs + 64], fc, tn2);
        tn3 = dot2(xnL[k2 * 128 + bs + 96], fc, tn3);
      }
      const float bb1 = biasB[ub * 2 + 1];
      tstg[ub * 128 + bs]      = f2h(tn0 + bb1);
      tstg[ub * 128 + bs + 32] = f2h(tn1 + bb1);
      tstg[ub * 128 + bs + 64] = f2h(tn2 + bb1);
      tstg[ub * 128 + bs + 96] = f2h(tn3 + bb1);
      __syncthreads();
      {
        unsigned* Tw = SB + (size_t)((isQ ? 6 : 4) + (cur ^ 1)) * 32768;
        for (int i = tid; i < 1024; i += 512) {
          int p = i >> 7, b = i & 127;
          Tw[(u0 / 2 + p) * 128 + b] =
              packss(tstg[(2 * p) * 128 + b], tstg[(2 * p + 1) * 128 + b]);
        }
      }
      if (isQ) {
        const int qslice = bid - 224;
        for (int i = tid; i < 3200; i += 512) {
          int b = i / 25, qi = i - b * 25;
          float s = 0.f;
#pragma unroll
          for (int e = 0; e < 16; ++e) s = fmaf(stL[e * 128 + b], U2[(size_t)qi * 512 + u0 + e], s);
          QPART[((size_t)qslice * 128 + b) * 25 + qi] = s;
        }
      }
      GBAR();   // barrier 1
      GBAR();   // barrier 2
    }
  }

  // ================= epilogue: logits + log_softmax =================
  if (bid < 128) {
    const int rr = bid;
    __syncthreads();
    float* hv = (float*)lds;        // 512
    float* part = hv + 512;         // 480
    float* lg = part + 480;         // 60
    {
      unsigned v = SB[(size_t)8 * 32768 + (tid >> 1) * 128 + rr];
      hv[tid] = (tid & 1) ? hhi(v) : hlo(v);
    }
    __syncthreads();
    if (tid < 480) {
      const int ci = tid >> 3, ks = tid & 7;
      const float* fr = f.fc_w + (size_t)ci * 512 + ks * 64;
      const float* hr = hv + ks * 64;
      float acc = 0.f;
      for (int j = 0; j < 64; j += 4) {
        const float4 fv = *(const float4*)(fr + j);
        const float4 hq = *(const float4*)(hr + j);
        acc += hq.x * fv.x + hq.y * fv.y + hq.z * fv.z + hq.w * fv.w;
      }
      part[ci * 8 + ks] = acc;
    }
    __syncthreads();
    if (tid < 60) {
      float s = f.fc_b[tid];
      for (int j = 0; j < 8; ++j) s += part[tid * 8 + j];
      lg[tid] = s;
    }
    __syncthreads();
    if (tid < 60) {
      float m = lg[0];
      for (int i2 = 1; i2 < 60; ++i2) m = fmaxf(m, lg[i2]);
      float ssum = 0.f;
      for (int i2 = 0; i2 < 60; ++i2) ssum += expf(lg[i2] - m);
      out_logp[(size_t)rr * C_ + tid] = lg[tid] - m - logf(ssum);
    }
  }
}

extern "C" void kernel_launch(void* const* d_in, const int* in_sizes, int n_in,
                              void* d_out, int out_size, void* d_ws, size_t ws_size,
                              hipStream_t stream) {
  if (ws_size < WS_BYTES) return;  // fail loudly (output stays poisoned)

  Full f;
  f.inputs = (const float*)d_in[0];
  f.Wih_t = (const float*)d_in[2];  f.Whh_t = (const float*)d_in[3];
  f.bih_t = (const float*)d_in[4];  f.bhh_t = (const float*)d_in[5];
  f.Wih_s = (const float*)d_in[6];  f.Whh_s = (const float*)d_in[7];
  f.bih_s = (const float*)d_in[8];  f.bhh_s = (const float*)d_in[9];
  f.Wih_1 = (const float*)d_in[10]; f.Whh_1 = (const float*)d_in[11];
  f.bih_1 = (const float*)d_in[12]; f.bhh_1 = (const float*)d_in[13];
  f.fc_w  = (const float*)d_in[14]; f.fc_b  = (const float*)d_in[15];
  f.fct_w = (const float*)d_in[16]; f.fct_b = (const float*)d_in[17];
  f.fc1_w = (const float*)d_in[18]; f.fc1_b = (const float*)d_in[19];
  f.fc2_w = (const float*)d_in[20]; f.fc2_b = (const float*)d_in[21];
  f.W_x_t = (const float*)d_in[22]; f.W_h_t = (const float*)d_in[23];
  f.b_t   = (const float*)d_in[24];
  f.W_x_s = (const float*)d_in[25]; f.W_h_s = (const float*)d_in[26];
  f.U_s   = (const float*)d_in[27]; f.b_s   = (const float*)d_in[28];
  f.b_us  = (const float*)d_in[29];
  f.ws = (char*)d_ws;
  f.out = (float*)d_out;

  hipLaunchKernelGGL(prep_pack, dim3(1024), dim3(256), 0, stream, f);
  hipLaunchKernelGGL(prep_state, dim3(128), dim3(512), 0, stream, f);

  void* args[] = { &f };
  hipLaunchCooperativeKernel((void*)scan11, dim3(256), dim3(512), args, 0, stream);
}

// Round 12
// 10174.820 us; speedup vs baseline: 5.3997x; 1.1515x over previous
//
#include <hip/hip_runtime.h>
#include <math.h>

#define B_ 128
#define T_ 128
#define IN_ 75
#define H_ 512
#define C_ 60
#define Q_ 25

// ---------------- workspace layout (bytes) ----------------
constexpr size_t OFF_WHHP = 0;          // uint4 [(c*256+k2)*512+u] f16 gate-pairs {i,f,g,o}
constexpr size_t OFF_WIHP = 6291456;    // uint4 [(c*38+k2)*512+u]  f16 gate-pairs (x-part)
constexpr size_t OFF_WXHP = 7225344;    // uint  [(w*256+k2)*512+u] f16 pairs, w: Wxt,Wht,Wxs,Whs
constexpr size_t OFF_FT2P = 9322496;    // uint  [(c*38+k2)*512+u]  f16 pairs, c: fct,fc1
constexpr size_t OFF_U2   = 9478144;    // float [25][512] (U_s @ fc2_w.T)
constexpr size_t OFF_B2   = 9529344;    // float [32]
constexpr size_t OFF_ST8  = 9529472;    // 9 x uint[256][128] state buffers (f16 pairs along k)
//   HT2[2] ; HS2[2] ; T12[2] ; T22[2] ; H12  (each 131072 B)
constexpr size_t OFF_BETA = 10709120;   // float [512][128]
constexpr size_t OFF_QP   = 10971264;   // float [2 gangs][32 slices][64*25]
constexpr size_t OFF_FLG  = 11380864;   // 256 flags x 64B + 2 gang GO lines
constexpr size_t WS_BYTES = 11397376;

struct Full {
  const float* inputs;
  const float* Wih_t; const float* Whh_t; const float* bih_t; const float* bhh_t;
  const float* Wih_s; const float* Whh_s; const float* bih_s; const float* bhh_s;
  const float* Wih_1; const float* Whh_1; const float* bih_1; const float* bhh_1;
  const float* fc_w;  const float* fc_b;
  const float* fct_w; const float* fct_b;
  const float* fc1_w; const float* fc1_b;
  const float* fc2_w; const float* fc2_b;
  const float* W_x_t; const float* W_h_t; const float* b_t;
  const float* W_x_s; const float* W_h_s; const float* U_s; const float* b_s; const float* b_us;
  char* ws; float* out;
};

typedef _Float16 h2t __attribute__((ext_vector_type(2)));
union U32H { unsigned u; h2t h; unsigned short s[2]; };

__device__ __forceinline__ float sigm(float v) { return 1.f / (1.f + expf(-v)); }
__device__ __forceinline__ float dot2(unsigned a, unsigned b, float c) {
#if __has_builtin(__builtin_amdgcn_fdot2)
  U32H A, B; A.u = a; B.u = b;
  return __builtin_amdgcn_fdot2(A.h, B.h, c, false);
#else
  U32H A, B; A.u = a; B.u = b;
  return fmaf((float)A.h.x, (float)B.h.x, fmaf((float)A.h.y, (float)B.h.y, c));
#endif
}
__device__ __forceinline__ unsigned pack2h(float a, float b) {
  U32H r; r.h.x = (_Float16)a; r.h.y = (_Float16)b; return r.u;
}
__device__ __forceinline__ float hlo(unsigned v) { U32H r; r.u = v; return (float)r.h.x; }
__device__ __forceinline__ float hhi(unsigned v) { U32H r; r.u = v; return (float)r.h.y; }

// ---------------- prep: pack weights (f16 pairs along k) ----------------
__global__ void prep_pack(Full f) {
  uint4* WHHP = (uint4*)(f.ws + OFF_WHHP);
  uint4* WIHP = (uint4*)(f.ws + OFF_WIHP);
  unsigned* WXHP = (unsigned*)(f.ws + OFF_WXHP);
  unsigned* FT2P = (unsigned*)(f.ws + OFF_FT2P);
  float* U2 = (float*)(f.ws + OFF_U2);
  float* B2 = (float*)(f.ws + OFF_B2);
  unsigned* FLG = (unsigned*)(f.ws + OFF_FLG);
  for (int i = blockIdx.x * blockDim.x + threadIdx.x; i < 4128; i += gridDim.x * blockDim.x)
    FLG[i] = 0u;

  const size_t N1 = (size_t)3 * 256 * 512;   // WHHP uint4
  const size_t N2 = (size_t)3 * 38 * 512;    // WIHP uint4
  const size_t N3 = (size_t)4 * 256 * 512;   // WXHP uint
  const size_t N4 = (size_t)2 * 38 * 512;    // FT2P uint
  const size_t N5 = (size_t)25 * 512;        // U2
  const size_t N6 = 25;                      // B2
  const size_t TOT = N1 + N2 + N3 + N4 + N5 + N6;
  for (size_t i = (size_t)blockIdx.x * blockDim.x + threadIdx.x; i < TOT;
       i += (size_t)gridDim.x * blockDim.x) {
    if (i < N1) {
      size_t c = i / 131072, r = i % 131072, k2 = r >> 9, u = r & 511;
      const float* W = (c == 0) ? f.Whh_t : (c == 1) ? f.Whh_s : f.Whh_1;
      uint4 v;
      v.x = pack2h(W[(0 * 512 + u) * 512 + 2 * k2], W[(0 * 512 + u) * 512 + 2 * k2 + 1]);
      v.y = pack2h(W[(1 * 512 + u) * 512 + 2 * k2], W[(1 * 512 + u) * 512 + 2 * k2 + 1]);
      v.z = pack2h(W[(2 * 512 + u) * 512 + 2 * k2], W[(2 * 512 + u) * 512 + 2 * k2 + 1]);
      v.w = pack2h(W[(3 * 512 + u) * 512 + 2 * k2], W[(3 * 512 + u) * 512 + 2 * k2 + 1]);
      WHHP[i] = v;
    } else if (i < N1 + N2) {
      size_t e = i - N1; size_t c = e / 19456, r = e % 19456, k2 = r >> 9, u = r & 511;
      const float* W = (c == 0) ? f.Wih_t : (c == 1) ? f.Wih_s : f.Wih_1;
      int k = 2 * (int)k2;
      uint4 v;
#pragma unroll
      for (int g = 0; g < 4; ++g) {
        float a = (k < 75) ? W[(g * 512 + u) * 75 + k] : 0.f;
        float b = (k + 1 < 75) ? W[(g * 512 + u) * 75 + k + 1] : 0.f;
        (&v.x)[g] = pack2h(a, b);
      }
      WIHP[e] = v;
    } else if (i < N1 + N2 + N3) {
      size_t e = i - N1 - N2; size_t w = e / 131072, r = e % 131072, k2 = r >> 9, u = r & 511;
      const float* W = (w == 0) ? f.W_x_t : (w == 1) ? f.W_h_t : (w == 2) ? f.W_x_s : f.W_h_s;
      WXHP[e] = pack2h(W[2 * k2 * 512 + u], W[(2 * k2 + 1) * 512 + u]);
    } else if (i < N1 + N2 + N3 + N4) {
      size_t e = i - N1 - N2 - N3; size_t c = e / 19456, r = e % 19456, k2 = r >> 9, u = r & 511;
      const float* W = c ? f.fc1_w : f.fct_w;
      int k = 2 * (int)k2;
      float a = (k < 75) ? W[u * 75 + k] : 0.f;
      float b = (k + 1 < 75) ? W[u * 75 + k + 1] : 0.f;
      FT2P[e] = pack2h(a, b);
    } else if (i < N1 + N2 + N3 + N4 + N5) {
      size_t e = i - N1 - N2 - N3 - N4; size_t qi = e >> 9, u = e & 511;
      float acc = 0.f;
      for (int n = 0; n < 512; ++n) acc = fmaf(f.U_s[u * 512 + n], f.fc2_w[qi * 512 + n], acc);
      U2[qi * 512 + u] = acc;
    } else {
      size_t qi = i - N1 - N2 - N3 - N4 - N5;
      float acc = f.fc2_b[qi];
      for (int n = 0; n < 512; ++n) acc = fmaf(f.b_us[n], f.fc2_w[qi * 512 + n], acc);
      B2[qi] = acc;
    }
  }
}

// ---------------- prep: initial state ----------------
__global__ __launch_bounds__(512) void prep_state(Full f) {
  const int b = blockIdx.x, j = threadIdx.x;
  __shared__ float x0[77];
  __shared__ float t1L[512], t2L[512];
  if (j < IN_) x0[j] = f.inputs[(size_t)b * T_ * IN_ + j];
  __syncthreads();
  float t1 = f.fct_b[j], t2 = f.fc1_b[j];
  for (int k = 0; k < IN_; ++k) {
    t1 = fmaf(x0[k], f.fct_w[j * IN_ + k], t1);
    t2 = fmaf(x0[k], f.fc1_w[j * IN_ + k], t2);
  }
  t1L[j] = t1; t2L[j] = t2;
  __syncthreads();
  unsigned* S = (unsigned*)(f.ws + OFF_ST8);
  if (j < 256) {
    S[0 * 32768 + j * 128 + b] = 0u;                                  // HT2[0]
    S[2 * 32768 + j * 128 + b] = 0u;                                  // HS2[0]
    S[8 * 32768 + j * 128 + b] = 0u;                                  // H12
    S[4 * 32768 + j * 128 + b] = pack2h(t1L[2 * j], t1L[2 * j + 1]);  // T12[0]
    S[6 * 32768 + j * 128 + b] = pack2h(t2L[2 * j], t2L[2 * j + 1]);  // T22[0]
  }
}

// ---------------- main persistent scan: 2 gangs x 128 blocks, 64 rows/gang ----------------
__global__ __launch_bounds__(512, 4) void scan12(Full f) {
  const int tid = threadIdx.x, bid = blockIdx.x;
  const int lane = tid & 63, wv = tid >> 6;
  const int gang = bid >> 7, bidg = bid & 127;
  const int rg = gang * 64 + lane;          // this thread's global batch row

  char* wsb = f.ws;
  const uint4* WHHP = (const uint4*)(wsb + OFF_WHHP);
  const uint4* WIHP = (const uint4*)(wsb + OFF_WIHP);
  const unsigned* WXHP = (const unsigned*)(wsb + OFF_WXHP);
  const unsigned* FT2P = (const unsigned*)(wsb + OFF_FT2P);
  const float* U2 = (const float*)(wsb + OFF_U2);
  const float* B2 = (const float*)(wsb + OFF_B2);
  unsigned* SB = (unsigned*)(wsb + OFF_ST8);
  float* BETA = (float*)(wsb + OFF_BETA);
  float* QPART = (float*)(wsb + OFF_QP);
  unsigned* FLG = (unsigned*)(wsb + OFF_FLG);

  float* out_logp = f.out;
  float* out_alpha = f.out + B_ * C_;
  float* out_beta = f.out + B_ * C_ + (size_t)T_ * B_ * Q_;

  __shared__ __align__(16) char lds[94208];

  unsigned bcount = 0;
  // gang-local barrier: release by arriving block leaders, gang leader aggregates, GO line per gang
#define GBAR() do { \
    ++bcount; \
    asm volatile("s_waitcnt vmcnt(0) lgkmcnt(0)" ::: "memory"); \
    __syncthreads(); \
    if (tid == 0) \
      __hip_atomic_store(&FLG[bid * 16], bcount, __ATOMIC_RELEASE, __HIP_MEMORY_SCOPE_AGENT); \
    if (bidg == 0) { \
      if (tid < 128) { \
        while (__hip_atomic_load(&FLG[(gang * 128 + tid) * 16], __ATOMIC_RELAXED, __HIP_MEMORY_SCOPE_AGENT) < bcount) \
          __builtin_amdgcn_s_sleep(2); \
      } \
      __syncthreads(); \
      if (tid == 0) \
        __hip_atomic_store(&FLG[(4096 >> 0) + gang * 16], bcount, __ATOMIC_RELEASE, __HIP_MEMORY_SCOPE_AGENT); \
    } \
    if (tid == 0) { \
      while (__hip_atomic_load(&FLG[4096 + gang * 16], __ATOMIC_RELAXED, __HIP_MEMORY_SCOPE_AGENT) < bcount) \
        __builtin_amdgcn_s_sleep(2); \
      (void)__hip_atomic_load(&FLG[4096 + gang * 16], __ATOMIC_ACQUIRE, __HIP_MEMORY_SCOPE_AGENT); \
    } \
    __syncthreads(); \
  } while (0)

  if (bidg < 64) {
    // ======== role T / S: cell GEMV, 16 units per block, unit pair per wave ========
    const int cell = bidg >> 5;                 // 0 = T, 1 = S
    const int u0 = (bidg & 31) * 16;
    uint4* WhhL = (uint4*)lds;                  // [256][16]  65536
    uint4* WxiL = (uint4*)(lds + 65536);        // [38][16]    9728
    unsigned* xL = (unsigned*)(lds + 75264);    // [38][64]    9728
    float* biasL = (float*)(lds + 84992);       // [16][4]      256

    for (int i = tid; i < 4096; i += 512) {
      int k2 = i >> 4, uu = i & 15;
      WhhL[i] = WHHP[((size_t)cell * 256 + k2) * 512 + u0 + uu];
    }
    for (int i = tid; i < 608; i += 512) {
      int k2 = i >> 4, uu = i & 15;
      WxiL[i] = WIHP[((size_t)cell * 38 + k2) * 512 + u0 + uu];
    }
    if (tid < 64) {
      int uu = tid >> 2, g = tid & 3;
      const float* bi = cell ? f.bih_s : f.bih_t;
      const float* bh = cell ? f.bhh_s : f.bhh_t;
      biasL[tid] = bi[g * 512 + u0 + uu] + bh[g * 512 + u0 + uu];
    }
    __syncthreads();

    float cc0 = 0.f, cc1 = 0.f;
    for (int t = 0; t < T_; ++t) {
      const int cur = t & 1;
      for (int i = tid; i < 2432; i += 512) {
        int k2 = i >> 6, b = i & 63;
        const size_t base = ((size_t)(gang * 64 + b) * T_ + t) * IN_;
        float xa = f.inputs[base + 2 * k2];
        float xb = (2 * k2 + 1 < IN_) ? f.inputs[base + 2 * k2 + 1] : 0.f;
        xL[i] = pack2h(xa, xb);
      }
      __syncthreads();
      const unsigned* Sr = SB + (size_t)(cell * 2 + cur) * 32768;
      float a00 = 0, a01 = 0, a02 = 0, a03 = 0, a10 = 0, a11 = 0, a12 = 0, a13 = 0;
#pragma unroll 4
      for (int k2 = 0; k2 < 256; ++k2) {
        const unsigned s = Sr[k2 * 128 + rg];
        const uint4 w0 = WhhL[k2 * 16 + 2 * wv];
        const uint4 w1 = WhhL[k2 * 16 + 2 * wv + 1];
        a00 = dot2(s, w0.x, a00); a01 = dot2(s, w0.y, a01);
        a02 = dot2(s, w0.z, a02); a03 = dot2(s, w0.w, a03);
        a10 = dot2(s, w1.x, a10); a11 = dot2(s, w1.y, a11);
        a12 = dot2(s, w1.z, a12); a13 = dot2(s, w1.w, a13);
      }
#pragma unroll 2
      for (int k2 = 0; k2 < 38; ++k2) {
        const unsigned xp = xL[k2 * 64 + lane];
        const uint4 w0 = WxiL[k2 * 16 + 2 * wv];
        const uint4 w1 = WxiL[k2 * 16 + 2 * wv + 1];
        a00 = dot2(xp, w0.x, a00); a01 = dot2(xp, w0.y, a01);
        a02 = dot2(xp, w0.z, a02); a03 = dot2(xp, w0.w, a03);
        a10 = dot2(xp, w1.x, a10); a11 = dot2(xp, w1.y, a11);
        a12 = dot2(xp, w1.z, a12); a13 = dot2(xp, w1.w, a13);
      }
      float h0, h1v;
      {
        const float* bl = &biasL[(2 * wv) * 4];
        const float iv = sigm(a00 + bl[0]), fv = sigm(a01 + bl[1]);
        const float gv = tanhf(a02 + bl[2]), ov = sigm(a03 + bl[3]);
        cc0 = fv * cc0 + iv * gv; h0 = ov * tanhf(cc0);
      }
      {
        const float* bl = &biasL[(2 * wv + 1) * 4];
        const float iv = sigm(a10 + bl[0]), fv = sigm(a11 + bl[1]);
        const float gv = tanhf(a12 + bl[2]), ov = sigm(a13 + bl[3]);
        cc1 = fv * cc1 + iv * gv; h1v = ov * tanhf(cc1);
      }
      unsigned* Sw = SB + (size_t)(cell * 2 + (cur ^ 1)) * 32768;
      Sw[(u0 / 2 + wv) * 128 + rg] = pack2h(h0, h1v);
      GBAR();   // bar1
      GBAR();   // bar2 (phase B empty)
    }
  } else if (bidg < 96) {
    // ======== role 1: gates1-h GEMV + alpha + cell1 ========
    const int u0 = (bidg - 64) * 16;
    uint4* WhhL = (uint4*)lds;                  // [256][16]  65536
    uint4* Wi1L = (uint4*)(lds + 65536);        // [38][16]    9728
    unsigned* xL = (unsigned*)(lds + 75264);    // [38][64]    9728
    float* qa = (float*)(lds + 84992);          // [64][25]    6400
    float* biasL = (float*)(lds + 91392);       // [16][4]      256
    float* B2L = (float*)(lds + 91648);         // [25]         100

    for (int i = tid; i < 4096; i += 512) {
      int k2 = i >> 4, uu = i & 15;
      WhhL[i] = WHHP[((size_t)2 * 256 + k2) * 512 + u0 + uu];
    }
    for (int i = tid; i < 608; i += 512) {
      int k2 = i >> 4, uu = i & 15;
      Wi1L[i] = WIHP[((size_t)2 * 38 + k2) * 512 + u0 + uu];
    }
    if (tid < 64) {
      int uu = tid >> 2, g = tid & 3;
      biasL[tid] = f.bih_1[g * 512 + u0 + uu] + f.bhh_1[g * 512 + u0 + uu];
    }
    if (tid < 25) B2L[tid] = B2[tid];
    __syncthreads();

    float cc0 = 0.f, cc1 = 0.f;
    for (int t = 0; t < T_; ++t) {
      for (int i = tid; i < 2432; i += 512) {
        int k2 = i >> 6, b = i & 63;
        const size_t base = ((size_t)(gang * 64 + b) * T_ + t) * IN_;
        float xa = f.inputs[base + 2 * k2];
        float xb = (2 * k2 + 1 < IN_) ? f.inputs[base + 2 * k2 + 1] : 0.f;
        xL[i] = pack2h(xa, xb);
      }
      __syncthreads();
      const unsigned* Hr = SB + (size_t)8 * 32768;
      float g00 = 0, g01 = 0, g02 = 0, g03 = 0, g10 = 0, g11 = 0, g12 = 0, g13 = 0;
#pragma unroll 4
      for (int k2 = 0; k2 < 256; ++k2) {
        const unsigned h = Hr[k2 * 128 + rg];
        const uint4 w0 = WhhL[k2 * 16 + 2 * wv];
        const uint4 w1 = WhhL[k2 * 16 + 2 * wv + 1];
        g00 = dot2(h, w0.x, g00); g01 = dot2(h, w0.y, g01);
        g02 = dot2(h, w0.z, g02); g03 = dot2(h, w0.w, g03);
        g10 = dot2(h, w1.x, g10); g11 = dot2(h, w1.y, g11);
        g12 = dot2(h, w1.z, g12); g13 = dot2(h, w1.w, g13);
      }
      {
        const float* bl = &biasL[(2 * wv) * 4];
        g00 += bl[0]; g01 += bl[1]; g02 += bl[2]; g03 += bl[3];
      }
      {
        const float* bl = &biasL[(2 * wv + 1) * 4];
        g10 += bl[0]; g11 += bl[1]; g12 += bl[2]; g13 += bl[3];
      }
      GBAR();   // bar1

      // ---- phase B: alpha + cell1 ----
      for (int i = tid; i < 1600; i += 512) {
        int row = i / 25;
        float s = B2L[i - row * 25];
#pragma unroll 8
        for (int s32 = 0; s32 < 32; ++s32)
          s += QPART[((size_t)(gang * 32 + s32)) * 1600 + i];
        qa[i] = s;
      }
      __syncthreads();
      if (tid < 64) {
        float* row = &qa[tid * 25];
        float m = row[0];
        for (int i2 = 1; i2 < 25; ++i2) m = fmaxf(m, row[i2]);
        float s = 0.f;
        for (int i2 = 0; i2 < 25; ++i2) { row[i2] = expf(row[i2] - m); s += row[i2]; }
        const float inv = 1.f / s;
        for (int i2 = 0; i2 < 25; ++i2) row[i2] *= inv;
      }
      __syncthreads();
      if (bidg == 64) {
        for (int i = tid; i < 1600; i += 512) {
          int row = i / 25;
          out_alpha[((size_t)t * B_ + gang * 64 + row) * Q_ + (i - row * 25)] = qa[i];
        }
      }
      float c00 = 0, c01 = 0, c02 = 0, c03 = 0, c10 = 0, c11 = 0, c12 = 0, c13 = 0;
      const float* ar = &qa[lane * 25];
      for (int k2 = 0; k2 < 38; ++k2) {
        const unsigned xp = xL[k2 * 64 + lane];
        const int k = 2 * k2;
        const int ai0 = k / 3;
        const int ai1 = (k + 1 < IN_) ? (k + 1) / 3 : 24;
        const float xge = hlo(xp) * ar[ai0];
        const float xgo = hhi(xp) * ar[ai1];
        const uint4 w0 = Wi1L[k2 * 16 + 2 * wv];
        const uint4 w1 = Wi1L[k2 * 16 + 2 * wv + 1];
        c00 = fmaf(xge, hlo(w0.x), c00); c00 = fmaf(xgo, hhi(w0.x), c00);
        c01 = fmaf(xge, hlo(w0.y), c01); c01 = fmaf(xgo, hhi(w0.y), c01);
        c02 = fmaf(xge, hlo(w0.z), c02); c02 = fmaf(xgo, hhi(w0.z), c02);
        c03 = fmaf(xge, hlo(w0.w), c03); c03 = fmaf(xgo, hhi(w0.w), c03);
        c10 = fmaf(xge, hlo(w1.x), c10); c10 = fmaf(xgo, hhi(w1.x), c10);
        c11 = fmaf(xge, hlo(w1.y), c11); c11 = fmaf(xgo, hhi(w1.y), c11);
        c12 = fmaf(xge, hlo(w1.z), c12); c12 = fmaf(xgo, hhi(w1.z), c12);
        c13 = fmaf(xge, hlo(w1.w), c13); c13 = fmaf(xgo, hhi(w1.w), c13);
      }
      float h0, h1v;
      {
        const float be = BETA[(size_t)(u0 + 2 * wv) * 128 + rg];
        const float i1 = sigm(c00 + g00), f1 = sigm(c01 + g01);
        const float gg = tanhf(c02 + g02), o1 = sigm(c03 + g03);
        cc0 = f1 * cc0 + i1 * gg;
        h0 = o1 * tanhf(cc0) * be;
      }
      {
        const float be = BETA[(size_t)(u0 + 2 * wv + 1) * 128 + rg];
        const float i1 = sigm(c10 + g10), f1 = sigm(c11 + g11);
        const float gg = tanhf(c12 + g12), o1 = sigm(c13 + g13);
        cc1 = f1 * cc1 + i1 * gg;
        h1v = o1 * tanhf(cc1) * be;
      }
      SB[(size_t)8 * 32768 + (u0 / 2 + wv) * 128 + rg] = pack2h(h0, h1v);
      GBAR();   // bar2
    }
  } else {
    // ======== role BQ: beta + st + q-partials (phase A), tmp-next (phase B) ========
    const int u0 = (bidg - 96) * 16;
    uint4* WXL = (uint4*)lds;                   // [256][16]  65536
    uint2* fcL = (uint2*)(lds + 65536);         // [38][16]    4864
    unsigned* xnL = (unsigned*)(lds + 70400);   // [38][64]    9728
    float* stL = (float*)(lds + 80128);         // [16][64]    4096
    float* U2L = (float*)(lds + 84224);         // [25][16]    1600
    float* biasQ = (float*)(lds + 85824);       // [16][2]      128
    float* biasF = (float*)(lds + 85952);       // [16][2]      128

    for (int i = tid; i < 4096; i += 512) {
      int k2 = i >> 4, uu = i & 15;
      uint4 v;
      v.x = WXHP[((size_t)0 * 256 + k2) * 512 + u0 + uu];
      v.y = WXHP[((size_t)1 * 256 + k2) * 512 + u0 + uu];
      v.z = WXHP[((size_t)2 * 256 + k2) * 512 + u0 + uu];
      v.w = WXHP[((size_t)3 * 256 + k2) * 512 + u0 + uu];
      WXL[i] = v;
    }
    for (int i = tid; i < 608; i += 512) {
      int k2 = i >> 4, uu = i & 15;
      uint2 v;
      v.x = FT2P[((size_t)0 * 38 + k2) * 512 + u0 + uu];
      v.y = FT2P[((size_t)1 * 38 + k2) * 512 + u0 + uu];
      fcL[i] = v;
    }
    for (int i = tid; i < 400; i += 512) {
      int q = i >> 4, e = i & 15;
      U2L[i] = U2[(size_t)q * 512 + u0 + e];
    }
    if (tid < 16) {
      int g = u0 + tid;
      biasQ[tid * 2] = f.b_s[g] + f.b_t[g];     // beta bias
      biasQ[tid * 2 + 1] = f.b_s[g];            // st bias
      biasF[tid * 2] = f.fct_b[g];
      biasF[tid * 2 + 1] = f.fc1_b[g];
    }
    __syncthreads();

    for (int t = 0; t < T_; ++t) {
      const int cur = t & 1;
      if (t < T_ - 1) {
        for (int i = tid; i < 2432; i += 512) {
          int k2 = i >> 6, b = i & 63;
          const size_t base = ((size_t)(gang * 64 + b) * T_ + t + 1) * IN_;
          float xa = f.inputs[base + 2 * k2];
          float xb = (2 * k2 + 1 < IN_) ? f.inputs[base + 2 * k2 + 1] : 0.f;
          xnL[i] = pack2h(xa, xb);
        }
      }
      __syncthreads();
      const unsigned* T1r = SB + (size_t)(4 + cur) * 32768;
      const unsigned* T2r = SB + (size_t)(6 + cur) * 32768;
      const unsigned* HTr = SB + (size_t)(0 + cur) * 32768;
      const unsigned* HSr = SB + (size_t)(2 + cur) * 32768;
      float aB0 = 0, aB1 = 0, aS0 = 0, aS1 = 0;
#pragma unroll 2
      for (int k2 = 0; k2 < 256; ++k2) {
        const unsigned t1 = T1r[k2 * 128 + rg];
        const unsigned ht = HTr[k2 * 128 + rg];
        const unsigned t2 = T2r[k2 * 128 + rg];
        const unsigned hs = HSr[k2 * 128 + rg];
        const uint4 w0 = WXL[k2 * 16 + 2 * wv];
        const uint4 w1 = WXL[k2 * 16 + 2 * wv + 1];
        aB0 = dot2(t1, w0.x, aB0); aB0 = dot2(ht, w0.y, aB0);
        aS0 = dot2(t2, w0.z, aS0); aS0 = dot2(hs, w0.w, aS0);
        aB1 = dot2(t1, w1.x, aB1); aB1 = dot2(ht, w1.y, aB1);
        aS1 = dot2(t2, w1.z, aS1); aS1 = dot2(hs, w1.w, aS1);
      }
      {
        const int uu = 2 * wv, u = u0 + uu;
        const float bv = fmaxf(aB0 + biasQ[uu * 2], 0.f);
        const float sv = tanhf(aS0 + biasQ[uu * 2 + 1]);
        BETA[(size_t)u * 128 + rg] = bv;
        out_beta[((size_t)t * B_ + rg) * H_ + u] = bv;
        stL[uu * 64 + lane] = sv;
      }
      {
        const int uu = 2 * wv + 1, u = u0 + uu;
        const float bv = fmaxf(aB1 + biasQ[uu * 2], 0.f);
        const float sv = tanhf(aS1 + biasQ[uu * 2 + 1]);
        BETA[(size_t)u * 128 + rg] = bv;
        out_beta[((size_t)t * B_ + rg) * H_ + u] = bv;
        stL[uu * 64 + lane] = sv;
      }
      __syncthreads();
      for (int i = tid; i < 1600; i += 512) {
        int row = i / 25, q = i - row * 25;
        float s = 0.f;
#pragma unroll
        for (int e = 0; e < 16; ++e) s = fmaf(stL[e * 64 + row], U2L[q * 16 + e], s);
        QPART[((size_t)(gang * 32 + (bidg - 96))) * 1600 + i] = s;
      }
      GBAR();   // bar1

      // ---- phase B: tmp-next ----
      if (t < T_ - 1) {
        float t10 = 0, t11 = 0, t20 = 0, t21 = 0;
#pragma unroll 2
        for (int k2 = 0; k2 < 38; ++k2) {
          const unsigned xp = xnL[k2 * 64 + lane];
          const uint2 f0 = fcL[k2 * 16 + 2 * wv];
          const uint2 f1 = fcL[k2 * 16 + 2 * wv + 1];
          t10 = dot2(xp, f0.x, t10); t20 = dot2(xp, f0.y, t20);
          t11 = dot2(xp, f1.x, t11); t21 = dot2(xp, f1.y, t21);
        }
        unsigned* T1w = SB + (size_t)(4 + (cur ^ 1)) * 32768;
        unsigned* T2w = SB + (size_t)(6 + (cur ^ 1)) * 32768;
        T1w[(u0 / 2 + wv) * 128 + rg] =
            pack2h(t10 + biasF[(2 * wv) * 2], t11 + biasF[(2 * wv + 1) * 2]);
        T2w[(u0 / 2 + wv) * 128 + rg] =
            pack2h(t20 + biasF[(2 * wv) * 2 + 1], t21 + biasF[(2 * wv + 1) * 2 + 1]);
      }
      GBAR();   // bar2
    }
  }

  // ================= epilogue: logits + log_softmax (one block per row) =================
  if (bidg < 64) {
    const int rr = gang * 64 + bidg;
    __syncthreads();
    float* hv = (float*)lds;        // 512
    float* part = hv + 512;         // 480
    float* lg = part + 480;         // 60
    {
      unsigned v = SB[(size_t)8 * 32768 + (tid >> 1) * 128 + rr];
      hv[tid] = (tid & 1) ? hhi(v) : hlo(v);
    }
    __syncthreads();
    if (tid < 480) {
      const int ci = tid >> 3, ks = tid & 7;
      const float* fr = f.fc_w + (size_t)ci * 512 + ks * 64;
      const float* hr = hv + ks * 64;
      float acc = 0.f;
      for (int j = 0; j < 64; j += 4) {
        const float4 fv = *(const float4*)(fr + j);
        const float4 hq = *(const float4*)(hr + j);
        acc += hq.x * fv.x + hq.y * fv.y + hq.z * fv.z + hq.w * fv.w;
      }
      part[ci * 8 + ks] = acc;
    }
    __syncthreads();
    if (tid < 60) {
      float s = f.fc_b[tid];
      for (int j = 0; j < 8; ++j) s += part[tid * 8 + j];
      lg[tid] = s;
    }
    __syncthreads();
    if (tid < 60) {
      float m = lg[0];
      for (int i2 = 1; i2 < 60; ++i2) m = fmaxf(m, lg[i2]);
      float ssum = 0.f;
      for (int i2 = 0; i2 < 60; ++i2) ssum += expf(lg[i2] - m);
      out_logp[(size_t)rr * C_ + tid] = lg[tid] - m - logf(ssum);
    }
  }
}

extern "C" void kernel_launch(void* const* d_in, const int* in_sizes, int n_in,
                              void* d_out, int out_size, void* d_ws, size_t ws_size,
                              hipStream_t stream) {
  if (ws_size < WS_BYTES) return;  // fail loudly (output stays poisoned)

  Full f;
  f.inputs = (const float*)d_in[0];
  f.Wih_t = (const float*)d_in[2];  f.Whh_t = (const float*)d_in[3];
  f.bih_t = (const float*)d_in[4];  f.bhh_t = (const float*)d_in[5];
  f.Wih_s = (const float*)d_in[6];  f.Whh_s = (const float*)d_in[7];
  f.bih_s = (const float*)d_in[8];  f.bhh_s = (const float*)d_in[9];
  f.Wih_1 = (const float*)d_in[10]; f.Whh_1 = (const float*)d_in[11];
  f.bih_1 = (const float*)d_in[12]; f.bhh_1 = (const float*)d_in[13];
  f.fc_w  = (const float*)d_in[14]; f.fc_b  = (const float*)d_in[15];
  f.fct_w = (const float*)d_in[16]; f.fct_b = (const float*)d_in[17];
  f.fc1_w = (const float*)d_in[18]; f.fc1_b = (const float*)d_in[19];
  f.fc2_w = (const float*)d_in[20]; f.fc2_b = (const float*)d_in[21];
  f.W_x_t = (const float*)d_in[22]; f.W_h_t = (const float*)d_in[23];
  f.b_t   = (const float*)d_in[24];
  f.W_x_s = (const float*)d_in[25]; f.W_h_s = (const float*)d_in[26];
  f.U_s   = (const float*)d_in[27]; f.b_s   = (const float*)d_in[28];
  f.b_us  = (const float*)d_in[29];
  f.ws = (char*)d_ws;
  f.out = (float*)d_out;

  hipLaunchKernelGGL(prep_pack, dim3(1024), dim3(256), 0, stream, f);
  hipLaunchKernelGGL(prep_state, dim3(128), dim3(512), 0, stream, f);

  void* args[] = { &f };
  hipLaunchCooperativeKernel((void*)scan12, dim3(256), dim3(512), args, 0, stream);
}

// Round 13
// 9807.903 us; speedup vs baseline: 5.6017x; 1.0374x over previous
//
#include <hip/hip_runtime.h>
#include <math.h>

#define B_ 128
#define T_ 128
#define IN_ 75
#define H_ 512
#define C_ 60
#define Q_ 25

// ---------------- workspace layout (bytes) ----------------
constexpr size_t OFF_WHHP = 0;          // uint4 [(c*256+k2)*512+u] f16 gate-pairs {i,f,g,o}
constexpr size_t OFF_WIHP = 6291456;    // uint4 [(c*38+k2)*512+u]  f16 gate-pairs (x-part; c2=Wih_1)
constexpr size_t OFF_WXHP = 7225344;    // uint  [(w*256+k2)*512+u] f16 pairs, w: Wxt,Wht,Wxs,Whs
constexpr size_t OFF_FT2P = 9322496;    // uint  [(c*38+k2)*512+u]  f16 pairs, c: fct,fc1
constexpr size_t OFF_U2   = 9478144;    // float [25][512] (U_s @ fc2_w.T)
constexpr size_t OFF_B2   = 9529344;    // float [32]
constexpr size_t OFF_XP   = 9529472;    // uint [t][38][128] f16 x-pairs
constexpr size_t OFF_HT2  = 12019840;   // uint [2][256][128]
constexpr size_t OFF_HS2  = 12281984;   // uint [2][256][128]
constexpr size_t OFF_T12  = 12544128;   // uint [2][256][128]
constexpr size_t OFF_T22  = 12806272;   // uint [2][256][128]
constexpr size_t OFF_H12  = 13068416;   // uint [256][128]
constexpr size_t OFF_CT   = 13199488;   // float [512][128]
constexpr size_t OFF_CS   = 13461632;   // float [512][128]
constexpr size_t OFF_C1   = 13723776;   // float [512][128]
constexpr size_t OFF_G1H  = 13985920;   // uint4 [256][128]
constexpr size_t OFF_ST   = 14510208;   // float [512][128]
constexpr size_t OFF_BETA = 14772352;   // float [512][128]
constexpr size_t WS_BYTES = 15034496;

struct Full {
  const float* inputs;
  const float* Wih_t; const float* Whh_t; const float* bih_t; const float* bhh_t;
  const float* Wih_s; const float* Whh_s; const float* bih_s; const float* bhh_s;
  const float* Wih_1; const float* Whh_1; const float* bih_1; const float* bhh_1;
  const float* fc_w;  const float* fc_b;
  const float* fct_w; const float* fct_b;
  const float* fc1_w; const float* fc1_b;
  const float* fc2_w; const float* fc2_b;
  const float* W_x_t; const float* W_h_t; const float* b_t;
  const float* W_x_s; const float* W_h_s; const float* U_s; const float* b_s; const float* b_us;
  char* ws; float* out;
};

typedef _Float16 h2t __attribute__((ext_vector_type(2)));
union U32H { unsigned u; h2t h; unsigned short s[2]; };

__device__ __forceinline__ float sigm(float v) { return 1.f / (1.f + expf(-v)); }
__device__ __forceinline__ float dot2(unsigned a, unsigned b, float c) {
#if __has_builtin(__builtin_amdgcn_fdot2)
  U32H A, B; A.u = a; B.u = b;
  return __builtin_amdgcn_fdot2(A.h, B.h, c, false);
#else
  U32H A, B; A.u = a; B.u = b;
  return fmaf((float)A.h.x, (float)B.h.x, fmaf((float)A.h.y, (float)B.h.y, c));
#endif
}
__device__ __forceinline__ unsigned pack2h(float a, float b) {
  U32H r; r.h.x = (_Float16)a; r.h.y = (_Float16)b; return r.u;
}
__device__ __forceinline__ float hlo(unsigned v) { U32H r; r.u = v; return (float)r.h.x; }
__device__ __forceinline__ float hhi(unsigned v) { U32H r; r.u = v; return (float)r.h.y; }

// ---------------- prep: pack weights + x-pairs ----------------
__global__ void prep_pack(Full f) {
  uint4* WHHP = (uint4*)(f.ws + OFF_WHHP);
  uint4* WIHP = (uint4*)(f.ws + OFF_WIHP);
  unsigned* WXHP = (unsigned*)(f.ws + OFF_WXHP);
  unsigned* FT2P = (unsigned*)(f.ws + OFF_FT2P);
  float* U2 = (float*)(f.ws + OFF_U2);
  float* B2 = (float*)(f.ws + OFF_B2);
  unsigned* XP = (unsigned*)(f.ws + OFF_XP);

  const size_t N1 = (size_t)3 * 256 * 512;   // WHHP
  const size_t N2 = (size_t)3 * 38 * 512;    // WIHP
  const size_t N3 = (size_t)4 * 256 * 512;   // WXHP
  const size_t N4 = (size_t)2 * 38 * 512;    // FT2P
  const size_t N5 = (size_t)25 * 512;        // U2
  const size_t N6 = 25;                      // B2
  const size_t N7 = (size_t)128 * 38 * 128;  // XP
  const size_t TOT = N1 + N2 + N3 + N4 + N5 + N6 + N7;
  for (size_t i = (size_t)blockIdx.x * blockDim.x + threadIdx.x; i < TOT;
       i += (size_t)gridDim.x * blockDim.x) {
    if (i < N1) {
      size_t c = i / 131072, r = i % 131072, k2 = r >> 9, u = r & 511;
      const float* W = (c == 0) ? f.Whh_t : (c == 1) ? f.Whh_s : f.Whh_1;
      uint4 v;
      v.x = pack2h(W[(0 * 512 + u) * 512 + 2 * k2], W[(0 * 512 + u) * 512 + 2 * k2 + 1]);
      v.y = pack2h(W[(1 * 512 + u) * 512 + 2 * k2], W[(1 * 512 + u) * 512 + 2 * k2 + 1]);
      v.z = pack2h(W[(2 * 512 + u) * 512 + 2 * k2], W[(2 * 512 + u) * 512 + 2 * k2 + 1]);
      v.w = pack2h(W[(3 * 512 + u) * 512 + 2 * k2], W[(3 * 512 + u) * 512 + 2 * k2 + 1]);
      WHHP[i] = v;
    } else if (i < N1 + N2) {
      size_t e = i - N1; size_t c = e / 19456, r = e % 19456, k2 = r >> 9, u = r & 511;
      const float* W = (c == 0) ? f.Wih_t : (c == 1) ? f.Wih_s : f.Wih_1;
      int k = 2 * (int)k2;
      uint4 v;
#pragma unroll
      for (int g = 0; g < 4; ++g) {
        float a = (k < 75) ? W[(g * 512 + u) * 75 + k] : 0.f;
        float b = (k + 1 < 75) ? W[(g * 512 + u) * 75 + k + 1] : 0.f;
        (&v.x)[g] = pack2h(a, b);
      }
      WIHP[e] = v;
    } else if (i < N1 + N2 + N3) {
      size_t e = i - N1 - N2; size_t w = e / 131072, r = e % 131072, k2 = r >> 9, u = r & 511;
      const float* W = (w == 0) ? f.W_x_t : (w == 1) ? f.W_h_t : (w == 2) ? f.W_x_s : f.W_h_s;
      WXHP[e] = pack2h(W[2 * k2 * 512 + u], W[(2 * k2 + 1) * 512 + u]);
    } else if (i < N1 + N2 + N3 + N4) {
      size_t e = i - N1 - N2 - N3; size_t c = e / 19456, r = e % 19456, k2 = r >> 9, u = r & 511;
      const float* W = c ? f.fc1_w : f.fct_w;
      int k = 2 * (int)k2;
      float a = (k < 75) ? W[u * 75 + k] : 0.f;
      float b = (k + 1 < 75) ? W[u * 75 + k + 1] : 0.f;
      FT2P[e] = pack2h(a, b);
    } else if (i < N1 + N2 + N3 + N4 + N5) {
      size_t e = i - N1 - N2 - N3 - N4; size_t qi = e >> 9, u = e & 511;
      float acc = 0.f;
      for (int n = 0; n < 512; ++n) acc = fmaf(f.U_s[u * 512 + n], f.fc2_w[qi * 512 + n], acc);
      U2[qi * 512 + u] = acc;
    } else if (i < N1 + N2 + N3 + N4 + N5 + N6) {
      size_t qi = i - N1 - N2 - N3 - N4 - N5;
      float acc = f.fc2_b[qi];
      for (int n = 0; n < 512; ++n) acc = fmaf(f.b_us[n], f.fc2_w[qi * 512 + n], acc);
      B2[qi] = acc;
    } else {
      size_t e = i - N1 - N2 - N3 - N4 - N5 - N6;
      size_t t = e / 4864, r = e % 4864, k2 = r >> 7, b = r & 127;
      int k = 2 * (int)k2;
      const size_t base = ((size_t)b * T_ + t) * IN_;
      float xa = (k < 75) ? f.inputs[base + k] : 0.f;
      float xb = (k + 1 < 75) ? f.inputs[base + k + 1] : 0.f;
      XP[e] = pack2h(xa, xb);
    }
  }
}

// ---------------- prep: initial state ----------------
__global__ __launch_bounds__(512) void prep_state(Full f) {
  const int b = blockIdx.x, j = threadIdx.x;
  __shared__ float x0[77];
  __shared__ float t1L[512], t2L[512];
  if (j < IN_) x0[j] = f.inputs[(size_t)b * T_ * IN_ + j];
  __syncthreads();
  float t1 = f.fct_b[j], t2 = f.fc1_b[j];
  for (int k = 0; k < IN_; ++k) {
    t1 = fmaf(x0[k], f.fct_w[j * IN_ + k], t1);
    t2 = fmaf(x0[k], f.fc1_w[j * IN_ + k], t2);
  }
  t1L[j] = t1; t2L[j] = t2;
  __syncthreads();
  ((float*)(f.ws + OFF_CT))[(size_t)j * 128 + b] = 0.f;
  ((float*)(f.ws + OFF_CS))[(size_t)j * 128 + b] = 0.f;
  ((float*)(f.ws + OFF_C1))[(size_t)j * 128 + b] = 0.f;
  if (j < 256) {
    ((unsigned*)(f.ws + OFF_HT2))[(size_t)j * 128 + b] = 0u;
    ((unsigned*)(f.ws + OFF_HS2))[(size_t)j * 128 + b] = 0u;
    ((unsigned*)(f.ws + OFF_H12))[(size_t)j * 128 + b] = 0u;
    ((unsigned*)(f.ws + OFF_T12))[(size_t)j * 128 + b] = pack2h(t1L[2 * j], t1L[2 * j + 1]);
    ((unsigned*)(f.ws + OFF_T22))[(size_t)j * 128 + b] = pack2h(t2L[2 * j], t2L[2 * j + 1]);
  }
}

// ---------------- K1: all K=512/1024 GEMVs + tmp-next, one timestep ----------------
__global__ __launch_bounds__(256) void k1(Full f, int t) {
  const int tid = threadIdx.x, bid = blockIdx.x;
  const int row = tid & 127, half = tid >> 7;
  const int cur = t & 1;

  char* wsb = f.ws;
  const uint4* WHHP = (const uint4*)(wsb + OFF_WHHP);
  const uint4* WIHP = (const uint4*)(wsb + OFF_WIHP);
  const unsigned* WXHP = (const unsigned*)(wsb + OFF_WXHP);
  const unsigned* FT2P = (const unsigned*)(wsb + OFF_FT2P);
  const unsigned* XP = (const unsigned*)(wsb + OFF_XP);
  unsigned* HT2 = (unsigned*)(wsb + OFF_HT2);
  unsigned* HS2 = (unsigned*)(wsb + OFF_HS2);
  unsigned* T12 = (unsigned*)(wsb + OFF_T12);
  unsigned* T22 = (unsigned*)(wsb + OFF_T22);
  unsigned* H12 = (unsigned*)(wsb + OFF_H12);
  float* CT = (float*)(wsb + OFF_CT);
  float* CS = (float*)(wsb + OFF_CS);
  uint4* G1H = (uint4*)(wsb + OFF_G1H);
  float* ST = (float*)(wsb + OFF_ST);
  float* BETA = (float*)(wsb + OFF_BETA);
  float* out_beta = f.out + B_ * C_ + (size_t)T_ * B_ * Q_;

  if (bid < 384) {
    // cells: c=0 (T), c=1 (S), c=2 (cell1 h-part)
    const int c = bid / 128;
    const int up = (bid % 128) * 2 + half;
    const int u0 = 2 * up, u1 = u0 + 1;
    const unsigned* Sr = (c == 0) ? (HT2 + (size_t)cur * 32768)
                       : (c == 1) ? (HS2 + (size_t)cur * 32768) : H12;
    float a0 = 0, a1 = 0, a2 = 0, a3 = 0, a4 = 0, a5 = 0, a6 = 0, a7 = 0;
#pragma unroll 4
    for (int k2 = 0; k2 < 256; ++k2) {
      const unsigned s = Sr[k2 * 128 + row];
      const uint4 w0 = WHHP[((size_t)(c * 256 + k2) << 9) + u0];
      const uint4 w1 = WHHP[((size_t)(c * 256 + k2) << 9) + u1];
      a0 = dot2(s, w0.x, a0); a1 = dot2(s, w0.y, a1);
      a2 = dot2(s, w0.z, a2); a3 = dot2(s, w0.w, a3);
      a4 = dot2(s, w1.x, a4); a5 = dot2(s, w1.y, a5);
      a6 = dot2(s, w1.z, a6); a7 = dot2(s, w1.w, a7);
    }
    if (c < 2) {
#pragma unroll 2
      for (int k2 = 0; k2 < 38; ++k2) {
        const unsigned xp = XP[((size_t)t * 38 + k2) * 128 + row];
        const uint4 w0 = WIHP[((size_t)(c * 38 + k2) << 9) + u0];
        const uint4 w1 = WIHP[((size_t)(c * 38 + k2) << 9) + u1];
        a0 = dot2(xp, w0.x, a0); a1 = dot2(xp, w0.y, a1);
        a2 = dot2(xp, w0.z, a2); a3 = dot2(xp, w0.w, a3);
        a4 = dot2(xp, w1.x, a4); a5 = dot2(xp, w1.y, a5);
        a6 = dot2(xp, w1.z, a6); a7 = dot2(xp, w1.w, a7);
      }
      const float* bi = c ? f.bih_s : f.bih_t;
      const float* bh = c ? f.bhh_s : f.bhh_t;
      float* Cst = c ? CS : CT;
      float h0, h1v;
      {
        const float iv = sigm(a0 + bi[u0] + bh[u0]);
        const float fv = sigm(a1 + bi[512 + u0] + bh[512 + u0]);
        const float gv = tanhf(a2 + bi[1024 + u0] + bh[1024 + u0]);
        const float ov = sigm(a3 + bi[1536 + u0] + bh[1536 + u0]);
        const float cc = fv * Cst[(size_t)u0 * 128 + row] + iv * gv;
        Cst[(size_t)u0 * 128 + row] = cc;
        h0 = ov * tanhf(cc);
      }
      {
        const float iv = sigm(a4 + bi[u1] + bh[u1]);
        const float fv = sigm(a5 + bi[512 + u1] + bh[512 + u1]);
        const float gv = tanhf(a6 + bi[1024 + u1] + bh[1024 + u1]);
        const float ov = sigm(a7 + bi[1536 + u1] + bh[1536 + u1]);
        const float cc = fv * Cst[(size_t)u1 * 128 + row] + iv * gv;
        Cst[(size_t)u1 * 128 + row] = cc;
        h1v = ov * tanhf(cc);
      }
      unsigned* Sw = (c ? HS2 : HT2) + (size_t)(cur ^ 1) * 32768;
      Sw[up * 128 + row] = pack2h(h0, h1v);
    } else {
      uint4 g;
      g.x = pack2h(a0 + f.bih_1[u0] + f.bhh_1[u0], a4 + f.bih_1[u1] + f.bhh_1[u1]);
      g.y = pack2h(a1 + f.bih_1[512 + u0] + f.bhh_1[512 + u0],
                   a5 + f.bih_1[512 + u1] + f.bhh_1[512 + u1]);
      g.z = pack2h(a2 + f.bih_1[1024 + u0] + f.bhh_1[1024 + u0],
                   a6 + f.bih_1[1024 + u1] + f.bhh_1[1024 + u1]);
      g.w = pack2h(a3 + f.bih_1[1536 + u0] + f.bhh_1[1536 + u0],
                   a7 + f.bih_1[1536 + u1] + f.bhh_1[1536 + u1]);
      G1H[(size_t)up * 128 + row] = g;
    }
  } else if (bid < 512) {
    // beta (K=1024) + tmp1-next
    const int up = (bid - 384) * 2 + half;
    const int u0 = 2 * up, u1 = u0 + 1;
    const unsigned* T1r = T12 + (size_t)cur * 32768;
    const unsigned* HTr = HT2 + (size_t)cur * 32768;
    float aB0 = 0, aB1 = 0;
#pragma unroll 4
    for (int k2 = 0; k2 < 256; ++k2) {
      const unsigned t1 = T1r[k2 * 128 + row];
      const unsigned ht = HTr[k2 * 128 + row];
      aB0 = dot2(t1, WXHP[((size_t)k2 << 9) + u0], aB0);
      aB0 = dot2(ht, WXHP[((size_t)(256 + k2) << 9) + u0], aB0);
      aB1 = dot2(t1, WXHP[((size_t)k2 << 9) + u1], aB1);
      aB1 = dot2(ht, WXHP[((size_t)(256 + k2) << 9) + u1], aB1);
    }
    {
      const float bv = fmaxf(aB0 + f.b_s[u0] + f.b_t[u0], 0.f);
      BETA[(size_t)u0 * 128 + row] = bv;
      out_beta[((size_t)t * B_ + row) * H_ + u0] = bv;
    }
    {
      const float bv = fmaxf(aB1 + f.b_s[u1] + f.b_t[u1], 0.f);
      BETA[(size_t)u1 * 128 + row] = bv;
      out_beta[((size_t)t * B_ + row) * H_ + u1] = bv;
    }
    if (t < T_ - 1) {
      float tn0 = 0, tn1 = 0;
#pragma unroll 2
      for (int k2 = 0; k2 < 38; ++k2) {
        const unsigned xp = XP[((size_t)(t + 1) * 38 + k2) * 128 + row];
        tn0 = dot2(xp, FT2P[((size_t)k2 << 9) + u0], tn0);
        tn1 = dot2(xp, FT2P[((size_t)k2 << 9) + u1], tn1);
      }
      T12[(size_t)(cur ^ 1) * 32768 + up * 128 + row] =
          pack2h(tn0 + f.fct_b[u0], tn1 + f.fct_b[u1]);
    }
  } else {
    // st (K=1024) + tmp2-next
    const int up = (bid - 512) * 2 + half;
    const int u0 = 2 * up, u1 = u0 + 1;
    const unsigned* T2r = T22 + (size_t)cur * 32768;
    const unsigned* HSr = HS2 + (size_t)cur * 32768;
    float aS0 = 0, aS1 = 0;
#pragma unroll 4
    for (int k2 = 0; k2 < 256; ++k2) {
      const unsigned t2 = T2r[k2 * 128 + row];
      const unsigned hs = HSr[k2 * 128 + row];
      aS0 = dot2(t2, WXHP[((size_t)(512 + k2) << 9) + u0], aS0);
      aS0 = dot2(hs, WXHP[((size_t)(768 + k2) << 9) + u0], aS0);
      aS1 = dot2(t2, WXHP[((size_t)(512 + k2) << 9) + u1], aS1);
      aS1 = dot2(hs, WXHP[((size_t)(768 + k2) << 9) + u1], aS1);
    }
    ST[(size_t)u0 * 128 + row] = tanhf(aS0 + f.b_s[u0]);
    ST[(size_t)u1 * 128 + row] = tanhf(aS1 + f.b_s[u1]);
    if (t < T_ - 1) {
      float tn0 = 0, tn1 = 0;
#pragma unroll 2
      for (int k2 = 0; k2 < 38; ++k2) {
        const unsigned xp = XP[((size_t)(t + 1) * 38 + k2) * 128 + row];
        tn0 = dot2(xp, FT2P[((size_t)(38 + k2) << 9) + u0], tn0);
        tn1 = dot2(xp, FT2P[((size_t)(38 + k2) << 9) + u1], tn1);
      }
      T22[(size_t)(cur ^ 1) * 32768 + up * 128 + row] =
          pack2h(tn0 + f.fc1_b[u0], tn1 + f.fc1_b[u1]);
    }
  }
}

// ---------------- K2: softmax/alpha + cell1, one timestep; block = one row ----------------
__global__ __launch_bounds__(256) void k2(Full f, int t) {
  const int tid = threadIdx.x, row = blockIdx.x;
  char* wsb = f.ws;
  const uint4* WIHP = (const uint4*)(wsb + OFF_WIHP);
  const float* U2 = (const float*)(wsb + OFF_U2);
  const float* B2 = (const float*)(wsb + OFF_B2);
  const float* ST = (const float*)(wsb + OFF_ST);
  const float* BETA = (const float*)(wsb + OFF_BETA);
  const uint4* G1H = (const uint4*)(wsb + OFF_G1H);
  float* C1 = (float*)(wsb + OFF_C1);
  unsigned* H12 = (unsigned*)(wsb + OFF_H12);
  float* out_alpha = f.out + B_ * C_;

  __shared__ float stv[512];
  __shared__ float qp[200];
  __shared__ float qv[25];
  __shared__ float al[25];
  __shared__ unsigned xgp[40];

  stv[tid] = ST[(size_t)tid * 128 + row];
  stv[tid + 256] = ST[(size_t)(tid + 256) * 128 + row];
  __syncthreads();
  if (tid < 200) {
    const int qi = tid >> 3, ks = tid & 7;
    const float* u2p = U2 + (size_t)qi * 512 + ks * 64;
    const float* sp = stv + ks * 64;
    float acc = 0.f;
    for (int j = 0; j < 64; j += 4) {
      const float4 uv = *(const float4*)(u2p + j);
      const float4 sv = *(const float4*)(sp + j);
      acc += sv.x * uv.x + sv.y * uv.y + sv.z * uv.z + sv.w * uv.w;
    }
    qp[tid] = acc;
  }
  __syncthreads();
  if (tid < 25) {
    float s = B2[tid];
    for (int j = 0; j < 8; ++j) s += qp[tid * 8 + j];
    qv[tid] = s;
  }
  __syncthreads();
  if (tid < 25) {
    float m = qv[0];
    for (int i2 = 1; i2 < 25; ++i2) m = fmaxf(m, qv[i2]);
    float s = 0.f;
    for (int i2 = 0; i2 < 25; ++i2) s += expf(qv[i2] - m);
    const float a = expf(qv[tid] - m) / s;
    al[tid] = a;
    out_alpha[((size_t)t * B_ + row) * Q_ + tid] = a;
  }
  __syncthreads();
  if (tid < 38) {
    const int k = 2 * tid;
    const size_t base = ((size_t)row * T_ + t) * IN_;
    const float xa = f.inputs[base + k] * al[k / 3];
    const float xb = (k + 1 < IN_) ? f.inputs[base + k + 1] * al[(k + 1) / 3] : 0.f;
    xgp[tid] = pack2h(xa, xb);
  }
  __syncthreads();
  // cell1: thread = unit-pair
  const int u0 = 2 * tid, u1 = u0 + 1;
  float c0 = 0, c1a = 0, c2 = 0, c3 = 0, c4 = 0, c5 = 0, c6 = 0, c7 = 0;
#pragma unroll 2
  for (int k2 = 0; k2 < 38; ++k2) {
    const unsigned xp = xgp[k2];
    const uint4 w0 = WIHP[((size_t)(2 * 38 + k2) << 9) + u0];
    const uint4 w1 = WIHP[((size_t)(2 * 38 + k2) << 9) + u1];
    c0 = dot2(xp, w0.x, c0); c1a = dot2(xp, w0.y, c1a);
    c2 = dot2(xp, w0.z, c2); c3 = dot2(xp, w0.w, c3);
    c4 = dot2(xp, w1.x, c4); c5 = dot2(xp, w1.y, c5);
    c6 = dot2(xp, w1.z, c6); c7 = dot2(xp, w1.w, c7);
  }
  const uint4 g = G1H[(size_t)tid * 128 + row];
  float h0, h1v;
  {
    const float i1 = sigm(c0 + hlo(g.x)), f1 = sigm(c1a + hlo(g.y));
    const float gg = tanhf(c2 + hlo(g.z)), o1 = sigm(c3 + hlo(g.w));
    const float cc = f1 * C1[(size_t)u0 * 128 + row] + i1 * gg;
    C1[(size_t)u0 * 128 + row] = cc;
    h0 = o1 * tanhf(cc) * BETA[(size_t)u0 * 128 + row];
  }
  {
    const float i1 = sigm(c4 + hhi(g.x)), f1 = sigm(c5 + hhi(g.y));
    const float gg = tanhf(c6 + hhi(g.z)), o1 = sigm(c7 + hhi(g.w));
    const float cc = f1 * C1[(size_t)u1 * 128 + row] + i1 * gg;
    C1[(size_t)u1 * 128 + row] = cc;
    h1v = o1 * tanhf(cc) * BETA[(size_t)u1 * 128 + row];
  }
  H12[(size_t)tid * 128 + row] = pack2h(h0, h1v);
}

// ---------------- K3: logits + log_softmax ----------------
__global__ __launch_bounds__(256) void k3(Full f) {
  const int tid = threadIdx.x, row = blockIdx.x;
  const unsigned* H12 = (const unsigned*)(f.ws + OFF_H12);
  __shared__ float hv[512];
  __shared__ float part[240];
  __shared__ float lg[60];
  {
    const unsigned v = H12[(size_t)tid * 128 + row];
    hv[2 * tid] = hlo(v);
    hv[2 * tid + 1] = hhi(v);
  }
  __syncthreads();
  if (tid < 240) {
    const int ci = tid >> 2, ks = tid & 3;
    const float* fr = f.fc_w + (size_t)ci * 512 + ks * 128;
    const float* hr = hv + ks * 128;
    float acc = 0.f;
    for (int j = 0; j < 128; j += 4) {
      const float4 fv = *(const float4*)(fr + j);
      const float4 hq = *(const float4*)(hr + j);
      acc += hq.x * fv.x + hq.y * fv.y + hq.z * fv.z + hq.w * fv.w;
    }
    part[tid] = acc;
  }
  __syncthreads();
  if (tid < 60) {
    float s = f.fc_b[tid];
    for (int j = 0; j < 4; ++j) s += part[tid * 4 + j];
    lg[tid] = s;
  }
  __syncthreads();
  if (tid < 60) {
    float m = lg[0];
    for (int i2 = 1; i2 < 60; ++i2) m = fmaxf(m, lg[i2]);
    float ssum = 0.f;
    for (int i2 = 0; i2 < 60; ++i2) ssum += expf(lg[i2] - m);
    f.out[(size_t)row * C_ + tid] = lg[tid] - m - logf(ssum);
  }
}

extern "C" void kernel_launch(void* const* d_in, const int* in_sizes, int n_in,
                              void* d_out, int out_size, void* d_ws, size_t ws_size,
                              hipStream_t stream) {
  if (ws_size < WS_BYTES) return;  // fail loudly (output stays poisoned)

  Full f;
  f.inputs = (const float*)d_in[0];
  f.Wih_t = (const float*)d_in[2];  f.Whh_t = (const float*)d_in[3];
  f.bih_t = (const float*)d_in[4];  f.bhh_t = (const float*)d_in[5];
  f.Wih_s = (const float*)d_in[6];  f.Whh_s = (const float*)d_in[7];
  f.bih_s = (const float*)d_in[8];  f.bhh_s = (const float*)d_in[9];
  f.Wih_1 = (const float*)d_in[10]; f.Whh_1 = (const float*)d_in[11];
  f.bih_1 = (const float*)d_in[12]; f.bhh_1 = (const float*)d_in[13];
  f.fc_w  = (const float*)d_in[14]; f.fc_b  = (const float*)d_in[15];
  f.fct_w = (const float*)d_in[16]; f.fct_b = (const float*)d_in[17];
  f.fc1_w = (const float*)d_in[18]; f.fc1_b = (const float*)d_in[19];
  f.fc2_w = (const float*)d_in[20]; f.fc2_b = (const float*)d_in[21];
  f.W_x_t = (const float*)d_in[22]; f.W_h_t = (const float*)d_in[23];
  f.b_t   = (const float*)d_in[24];
  f.W_x_s = (const float*)d_in[25]; f.W_h_s = (const float*)d_in[26];
  f.U_s   = (const float*)d_in[27]; f.b_s   = (const float*)d_in[28];
  f.b_us  = (const float*)d_in[29];
  f.ws = (char*)d_ws;
  f.out = (float*)d_out;

  hipLaunchKernelGGL(prep_pack, dim3(1024), dim3(256), 0, stream, f);
  hipLaunchKernelGGL(prep_state, dim3(128), dim3(512), 0, stream, f);

  for (int t = 0; t < T_; ++t) {
    hipLaunchKernelGGL(k1, dim3(640), dim3(256), 0, stream, f, t);
    hipLaunchKernelGGL(k2, dim3(128), dim3(256), 0, stream, f, t);
  }
  hipLaunchKernelGGL(k3, dim3(128), dim3(256), 0, stream, f);
}